// Round 10
// baseline (332.573 us; speedup 1.0000x reference)
//
#include <hip/hip_runtime.h>
#include <cstdint>
#include <cstddef>

#define CDIV(a,b) (((a)+(b)-1)/(b))
constexpr int NG = 64;
constexpr int CAP = 64;     // fixed in-edge capacity per node (Poisson(16): P(>64) ~ 1e-20)
constexpr int RBITS = 11;   // 2048 nodes per dst-range
constexpr int NRMAX = 64;

typedef _Float16 h4 __attribute__((ext_vector_type(4)));
typedef _Float16 h8 __attribute__((ext_vector_type(8)));
typedef float f4 __attribute__((ext_vector_type(4)));

__global__ void k_zero(int* p, long n) {
  long i = (long)blockIdx.x*blockDim.x + threadIdx.x;
  long stride = (long)gridDim.x*blockDim.x;
  for (; i < n; i += stride) p[i] = 0;
}

// phase 1: partition edges by dst-range; packed 4B records (dlocal<<17 | src), per-range regions
__global__ __launch_bounds__(256) void k_part(
    const int* __restrict__ src, const int* __restrict__ dst,
    int* __restrict__ rngcur, unsigned* __restrict__ part,
    int E, int RCAP) {
  __shared__ int hcnt[NRMAX], hbase[NRMAX], hfill[NRMAX];
  int tid = threadIdx.x;
  int base = blockIdx.x * 4096;
  if (tid < NRMAX) hcnt[tid] = 0;
  __syncthreads();
  unsigned val[16]; int rr[16];
  #pragma unroll
  for (int u = 0; u < 16; u++) {
    int e = base + u*256 + tid;
    rr[u] = -1;
    if (e < E) {
      int s = src[e], d = dst[e];
      rr[u] = d >> RBITS;
      val[u] = ((unsigned)(d & ((1<<RBITS)-1)) << 17) | (unsigned)s;
      atomicAdd(&hcnt[rr[u]], 1);
    }
  }
  __syncthreads();
  if (tid < NRMAX) {
    hfill[tid] = 0;
    if (hcnt[tid]) hbase[tid] = atomicAdd(&rngcur[tid], hcnt[tid]);
  }
  __syncthreads();
  #pragma unroll
  for (int u = 0; u < 16; u++) {
    if (rr[u] >= 0) {
      int p = hbase[rr[u]] + atomicAdd(&hfill[rr[u]], 1);
      if (p < RCAP) part[(size_t)rr[u]*RCAP + p] = val[u];
    }
  }
}

// phase 2: one block per range; scatter into L2-resident 512KB ecol window
__global__ __launch_bounds__(1024) void k_scat(
    const unsigned* __restrict__ part, const int* __restrict__ rngcur,
    int* __restrict__ icnt, int* __restrict__ ecol, int RCAP) {
  int r = blockIdx.x;
  int cnt = min(rngcur[r], RCAP);
  int n0 = r << RBITS;
  const unsigned* p = part + (size_t)r*RCAP;
  for (int i = threadIdx.x; i < cnt; i += 1024) {
    unsigned v = p[i];
    int s = (int)(v & 131071u);
    int d = n0 + (int)(v >> 17);
    int q = atomicAdd(&icnt[d], 1);
    if (q < CAP) ecol[(size_t)d*CAP + q] = s;
  }
}

// per-node: clamp count, dinv = rsqrt(deg) with deg = c+1 (incl self), graph histogram
__global__ void k_node2(int* __restrict__ icnt, const int* __restrict__ batch,
                        float* __restrict__ dinv, int* __restrict__ cnt_g, int n) {
  __shared__ int hist[NG];
  int tid = threadIdx.x;
  int i = blockIdx.x*256 + tid;
  if (tid < NG) hist[tid] = 0;
  __syncthreads();
  if (i < n) {
    int c = min(icnt[i], CAP);
    icnt[i] = c;
    dinv[i] = rsqrtf((float)(c + 1));
    atomicAdd(&hist[batch[i]], 1);
  }
  __syncthreads();
  if (tid < NG && hist[tid]) atomicAdd(&cnt_g[tid], hist[tid]);
}

// W[K x nout] fp32 -> WT[nout x K] fp16
__global__ void k_wcvt(const float* __restrict__ W, _Float16* __restrict__ WT,
                       int K, int nout) {
  int idx = blockIdx.x*256 + threadIdx.x;
  if (idx >= K*nout) return;
  int c = idx / K, k = idx % K;
  WT[idx] = (_Float16)W[(size_t)k*nout + c];
}

// unweighted gather on premultiplied features: out[i] = dinv[i]*(sum_e y[s_e] + y[i])
// L1: out = dinv*relu(dinv*sum + bias)  (extra dinv premultiplies for next gather)
template<int F, bool L1>
__global__ __launch_bounds__(256) void k_gather_x(
    const _Float16* __restrict__ y, _Float16* __restrict__ z,
    const int* __restrict__ ecol, const int* __restrict__ icnt,
    const float* __restrict__ dinv, const float* __restrict__ bias, int n) {
  constexpr int LPN = F / 4;
  constexpr int NPW = 64 / LPN;
  int wid = (int)((blockIdx.x*(size_t)blockDim.x + threadIdx.x) >> 6);
  int lane = threadIdx.x & 63;
  int sub = lane / LPN;
  int li  = lane % LPN;
  int gw = wid * NPW + sub;
  if (gw >= n) return;
  float di = dinv[gw];
  h4 sv = *(const h4*)(y + (size_t)gw*F + li*4);
  float a0 = (float)sv.x, a1 = (float)sv.y, a2 = (float)sv.z, a3 = (float)sv.w;
  int cnt = icnt[gw];
  const int* col = ecol + (size_t)gw * CAP;
  int k = 0;
  for (; k + 7 < cnt; k += 8) {
    int c[8];
    #pragma unroll
    for (int u = 0; u < 8; u++) c[u] = col[k + u];
    #pragma unroll
    for (int u = 0; u < 8; u++) {
      h4 v = *(const h4*)(y + (size_t)c[u]*F + li*4);
      a0 += (float)v.x; a1 += (float)v.y; a2 += (float)v.z; a3 += (float)v.w;
    }
  }
  for (; k < cnt; k++) {
    h4 v = *(const h4*)(y + (size_t)col[k]*F + li*4);
    a0 += (float)v.x; a1 += (float)v.y; a2 += (float)v.z; a3 += (float)v.w;
  }
  if constexpr (L1) {
    a0 = di * fmaxf(di*a0 + bias[li*4+0], 0.f);
    a1 = di * fmaxf(di*a1 + bias[li*4+1], 0.f);
    a2 = di * fmaxf(di*a2 + bias[li*4+2], 0.f);
    a3 = di * fmaxf(di*a3 + bias[li*4+3], 0.f);
  } else {
    a0 *= di; a1 *= di; a2 *= di; a3 *= di;
  }
  h4 o; o.x = (_Float16)a0; o.y = (_Float16)a1; o.z = (_Float16)a2; o.w = (_Float16)a3;
  *(h4*)(z + (size_t)gw*F + li*4) = o;
}

// MFMA GEMM: C[n x NOUT] = A[n x K] @ W, NOUT = CF*64, block = 64 rows x NOUT.
// EPI: 0=store (x rowscale), 1=bias+relu (x rowscale) store, 2=bias+relu + fused graph pool
// AF32: A is fp32 (converted to fp16 during staging). rs: optional per-row scale (dinv).
template<int K, int CF, int EPI, bool AF32>
__global__ __launch_bounds__(256, 2) void k_mgemm(
    const void* __restrict__ Av, const _Float16* __restrict__ WT,
    const float* __restrict__ bias, _Float16* __restrict__ C,
    int n, const int* __restrict__ batch, float* __restrict__ gsum,
    const float* __restrict__ rs) {
  constexpr int KS = K / 32;
  constexpr int NOUT = CF * 64;
  constexpr int LDA = K + 8;
  __shared__ __align__(16) _Float16 sA[64][LDA];
  __shared__ float red[4][256];
  __shared__ int sBatch[64];
  int tid = threadIdx.x;
  int row0 = blockIdx.x * 64;
  int lane = tid & 63, wv = tid >> 6;
  int grp = lane >> 4, l16 = lane & 15;
  int wcol0 = wv * (CF * 16);

  {
    int srow = tid >> 2;
    bool ok = (row0 + srow) < n;
    if constexpr (AF32) {
      const float* A = (const float*)Av;
      #pragma unroll
      for (int u = 0; u < K/16; u++) {
        int c4 = (tid & 3) + 4*u;
        float4 v = ok ? *(const float4*)(A + (size_t)(row0+srow)*K + c4*4)
                      : make_float4(0.f,0.f,0.f,0.f);
        h4 o; o.x=(_Float16)v.x; o.y=(_Float16)v.y; o.z=(_Float16)v.z; o.w=(_Float16)v.w;
        *(h4*)&sA[srow][c4*4] = o;
      }
    } else {
      const _Float16* A = (const _Float16*)Av;
      #pragma unroll
      for (int u = 0; u < K/32; u++) {
        int c8 = (tid & 3) + 4*u;
        h8 v = {};
        if (ok) v = *(const h8*)(A + (size_t)(row0+srow)*K + c8*8);
        *(h8*)&sA[srow][c8*8] = v;
      }
    }
  }
  if constexpr (EPI == 2) {
    if (tid < 64) sBatch[tid] = (row0 + tid < n) ? batch[row0 + tid] : -1;
  }

  h8 bfrag[KS][CF];
  #pragma unroll
  for (int ks = 0; ks < KS; ks++)
    #pragma unroll
    for (int cf = 0; cf < CF; cf++) {
      int col = wcol0 + cf*16 + l16;
      bfrag[ks][cf] = *(const h8*)(WT + (size_t)col*K + ks*32 + grp*8);
    }

  f4 acc[4][CF] = {};
  __syncthreads();

  #pragma unroll
  for (int ks = 0; ks < KS; ks++) {
    h8 af[4];
    #pragma unroll
    for (int rf = 0; rf < 4; rf++)
      af[rf] = *(const h8*)&sA[rf*16 + l16][ks*32 + grp*8];
    #pragma unroll
    for (int rf = 0; rf < 4; rf++)
      #pragma unroll
      for (int cf = 0; cf < CF; cf++)
        acc[rf][cf] = __builtin_amdgcn_mfma_f32_16x16x32_f16(
            af[rf], bfrag[ks][cf], acc[rf][cf], 0, 0, 0);
  }

  if constexpr (EPI <= 1) {
    #pragma unroll
    for (int rf = 0; rf < 4; rf++) {
      #pragma unroll
      for (int r = 0; r < 4; r++) {
        int row = row0 + rf*16 + grp*4 + r;
        if (row < n) {
          float rsv = rs ? rs[row] : 1.f;
          #pragma unroll
          for (int cf = 0; cf < CF; cf++) {
            int col = wcol0 + cf*16 + l16;
            float v = acc[rf][cf][r];
            if constexpr (EPI == 1) v = fmaxf(v + bias[col], 0.f);
            v *= rsv;
            C[(size_t)row*NOUT + col] = (_Float16)v;
          }
        }
      }
    }
  } else {
    float bv[CF];
    #pragma unroll
    for (int cf = 0; cf < CF; cf++) bv[cf] = bias[wcol0 + cf*16 + l16];
    #pragma unroll
    for (int rf = 0; rf < 4; rf++)
      #pragma unroll
      for (int cf = 0; cf < CF; cf++)
        #pragma unroll
        for (int r = 0; r < 4; r++)
          acc[rf][cf][r] = fmaxf(acc[rf][cf][r] + bv[cf], 0.f);
    __syncthreads();
    int g0 = sBatch[0];
    int g1 = batch[min(row0 + 63, n - 1)];
    for (int g = g0; g <= g1; ++g) {
      float p[CF] = {};
      #pragma unroll
      for (int rf = 0; rf < 4; rf++)
        #pragma unroll
        for (int r = 0; r < 4; r++) {
          int lrow = rf*16 + grp*4 + r;
          bool m = (sBatch[lrow] == g);
          #pragma unroll
          for (int cf = 0; cf < CF; cf++)
            if (m) p[cf] += acc[rf][cf][r];
        }
      #pragma unroll
      for (int cf = 0; cf < CF; cf++)
        red[grp][wcol0 + cf*16 + l16] = p[cf];
      __syncthreads();
      if (tid < NOUT) {
        float s = red[0][tid] + red[1][tid] + red[2][tid] + red[3][tid];
        atomicAdd(&gsum[g*256 + tid], s);
      }
      __syncthreads();
    }
  }
}

__device__ __forceinline__ float sigm(float x) { return 1.f / (1.f + expf(-x)); }

// gates[g][j] for j in [0,1024): [0,512)=forward, [512,1024)=backward.
__global__ __launch_bounds__(256) void k_gates(
    const float* __restrict__ gsum, const int* __restrict__ cnt_g,
    const float* __restrict__ wf, const float* __restrict__ bf,
    const float* __restrict__ wb, const float* __restrict__ bb,
    float* __restrict__ gates) {
  int g = blockIdx.y;
  int j0 = blockIdx.x * 64;
  int tid = threadIdx.x;
  __shared__ float pooled[256];
  float invc = 1.0f / fmaxf((float)cnt_g[g], 1.0f);
  pooled[tid] = gsum[g*256 + tid] * invc;
  __syncthreads();
  int jl = tid >> 2, ks = tid & 3;
  int j = j0 + jl;
  const float* wrow;
  float bias;
  if (j < 512) { wrow = wf + (size_t)j*256;        bias = bf[j]; }
  else         { wrow = wb + (size_t)(j-512)*256;  bias = bb[j-512]; }
  const float4* w4 = (const float4*)(wrow + ks*64);
  const float4* p4 = (const float4*)(&pooled[ks*64]);
  float acc = 0.f;
  #pragma unroll
  for (int i = 0; i < 16; i++) {
    float4 a = w4[i], b = p4[i];
    acc += a.x*b.x + a.y*b.y + a.z*b.z + a.w*b.w;
  }
  acc += __shfl_xor(acc, 1, 64);
  acc += __shfl_xor(acc, 2, 64);
  if (ks == 0) gates[(size_t)g*1024 + j] = acc + bias;
}

// LSTM nonlinearity (T=1, zero state) + FC strip of 125 columns.
__global__ __launch_bounds__(256) void k_lstmfc(
    const float* __restrict__ gates, const float* __restrict__ fw,
    const float* __restrict__ fb, float* __restrict__ logits) {
  int g = blockIdx.y;
  int c0 = blockIdx.x * 125;
  int tid = threadIdx.x;
  __shared__ float gg[1024];
  __shared__ float lstm[256];
  __shared__ float sred[256];
  #pragma unroll
  for (int u = 0; u < 4; u++) gg[tid + u*256] = gates[(size_t)g*1024 + tid + u*256];
  __syncthreads();
  if (tid < 128) {
    float i = gg[tid], z = gg[256+tid], o = gg[384+tid];
    float cc = sigm(i)*tanhf(z);
    lstm[tid] = sigm(o)*tanhf(cc);
  } else {
    int u = tid - 128;
    float i = gg[512+u], z = gg[768+u], o = gg[896+u];
    float cc = sigm(i)*tanhf(z);
    lstm[128+u] = sigm(o)*tanhf(cc);
  }
  __syncthreads();
  int kh = tid >> 7;
  int cl = tid & 127;
  float acc = 0.f;
  if (cl < 125) {
    const float* fcol = fw + (size_t)kh*128*500 + (c0 + cl);
    #pragma unroll 8
    for (int k = 0; k < 128; k++)
      acc += lstm[kh*128 + k] * fcol[(size_t)k*500];
  }
  sred[tid] = acc;
  __syncthreads();
  if (tid < 125)
    logits[(size_t)g*500 + c0 + tid] = sred[tid] + sred[tid+128] + fb[c0 + tid];
}

// log_softmax over 500 logits per graph
__global__ __launch_bounds__(256) void k_smax(
    const float* __restrict__ logits, float* __restrict__ out) {
  int g = blockIdx.x, tid = threadIdx.x;
  __shared__ float sred[256];
  float l0 = logits[(size_t)g*500 + tid];
  float l1 = (tid < 244) ? logits[(size_t)g*500 + 256 + tid] : -1e30f;
  float m = fmaxf(l0, l1);
  sred[tid] = m; __syncthreads();
  for (int d = 128; d > 0; d >>= 1) {
    if (tid < d) sred[tid] = fmaxf(sred[tid], sred[tid+d]);
    __syncthreads();
  }
  float mx = sred[0]; __syncthreads();
  float s = expf(l0 - mx) + ((tid < 244) ? expf(l1 - mx) : 0.f);
  sred[tid] = s; __syncthreads();
  for (int d = 128; d > 0; d >>= 1) {
    if (tid < d) sred[tid] += sred[tid+d];
    __syncthreads();
  }
  float lse = logf(sred[0]) + mx;
  out[(size_t)g*500 + tid] = l0 - lse;
  if (tid < 244) out[(size_t)g*500 + 256 + tid] = l1 - lse;
}

extern "C" void kernel_launch(void* const* d_in, const int* in_sizes, int n_in,
                              void* d_out, int out_size, void* d_ws, size_t ws_size,
                              hipStream_t stream) {
  const float* x     = (const float*)d_in[0];
  const int*   ei    = (const int*)d_in[1];
  const int*   batch = (const int*)d_in[2];
  const float* W1 = (const float*)d_in[3];  const float* b1 = (const float*)d_in[4];
  const float* W2 = (const float*)d_in[5];  const float* b2 = (const float*)d_in[6];
  const float* W3 = (const float*)d_in[7];  const float* b3 = (const float*)d_in[8];
  const float* wf = (const float*)d_in[9];  const float* bf = (const float*)d_in[11];
  const float* wb = (const float*)d_in[12]; const float* bb = (const float*)d_in[14];
  const float* fw = (const float*)d_in[15]; const float* fb = (const float*)d_in[16];
  int N = in_sizes[2];
  int E = in_sizes[1] / 2;
  const int* src = ei;
  const int* dst = ei + E;
  int NR = CDIV(N, 1 << RBITS);            // 49 ranges
  int RCAP = CDIV(E, NR) + 4096;           // mean + ~22 sigma headroom

  char* w = (char*)d_ws;
  auto alloc = [&](size_t bytes) { char* p = w; w += (bytes + 255) / 256 * 256; return p; };
  int*   icnt   = (int*)  alloc((size_t)N*4);
  int*   cnt_g  = (int*)  alloc(NG*4);
  int*   rngcur = (int*)  alloc(NRMAX*4);
  float* gsum   = (float*)alloc(NG*256*4);
  char*  zero_end = w;
  float* dinv  = (float*)alloc((size_t)N*4);
  unsigned* part = (unsigned*)alloc((size_t)NR*RCAP*4);
  int*   ecol  = (int*)  alloc((size_t)N*CAP*4);
  _Float16* B0h = (_Float16*)alloc((size_t)N*128*2);
  _Float16* B1h = (_Float16*)alloc((size_t)N*128*2);
  _Float16* WT1 = (_Float16*)alloc(128*64*2);
  _Float16* WT2 = (_Float16*)alloc(64*128*2);
  _Float16* WT3 = (_Float16*)alloc(128*256*2);
  float* gates  = (float*)alloc((size_t)NG*1024*4);
  float* logits = (float*)alloc((size_t)NG*500*4);

  long zwords = (zero_end - (char*)icnt) / 4;
  k_zero<<<256, 256, 0, stream>>>(icnt, zwords);
  k_part<<<CDIV(E,4096), 256, 0, stream>>>(src, dst, rngcur, part, E, RCAP);
  k_scat<<<NR, 1024, 0, stream>>>(part, rngcur, icnt, ecol, RCAP);
  k_node2<<<CDIV(N,256), 256, 0, stream>>>(icnt, batch, dinv, cnt_g, N);
  k_wcvt<<<CDIV(128*64,256), 256, 0, stream>>>(W1, WT1, 128, 64);
  k_wcvt<<<CDIV(64*128,256), 256, 0, stream>>>(W2, WT2, 64, 128);
  k_wcvt<<<CDIV(128*256,256), 256, 0, stream>>>(W3, WT3, 128, 256);

  // layer 1: y~1 = dinv*(x @ W1)   (MFMA fp32->fp16, rowscale fused)
  k_mgemm<128,1,0,true><<<CDIV(N,64), 256, 0, stream>>>(x, WT1, nullptr, B0h, N, nullptr, nullptr, dinv);
  // gather1: h~1 = dinv*relu(dinv*(sum + self) + b1)
  k_gather_x<64,true><<<CDIV(N,16), 256, 0, stream>>>(B0h, B1h, ecol, icnt, dinv, b1, N);
  // gather2: z2 = dinv*(sum + self)
  k_gather_x<64,false><<<CDIV(N,16), 256, 0, stream>>>(B1h, B0h, ecol, icnt, dinv, nullptr, N);
  // h~2 = dinv*relu(z2 @ W2 + b2)
  k_mgemm<64,2,1,false><<<CDIV(N,64), 256, 0, stream>>>(B0h, WT2, b2, B1h, N, nullptr, nullptr, dinv);
  // gather3: z3 = dinv*(sum + self)
  k_gather_x<128,false><<<CDIV(N,8), 256, 0, stream>>>(B1h, B0h, ecol, icnt, dinv, nullptr, N);
  // relu(z3 @ W3 + b3) + fused graph pooling
  k_mgemm<128,4,2,false><<<CDIV(N,64), 256, 0, stream>>>(B0h, WT3, b3, nullptr, N, batch, gsum, nullptr);
  // head
  k_gates<<<dim3(16, NG), 256, 0, stream>>>(gsum, cnt_g, wf, bf, wb, bb, gates);
  k_lstmfc<<<dim3(4, NG), 256, 0, stream>>>(gates, fw, fb, logits);
  k_smax<<<NG, 256, 0, stream>>>(logits, (float*)d_out);
}

// Round 11
// 268.864 us; speedup vs baseline: 1.2370x; 1.2370x over previous
//
#include <hip/hip_runtime.h>
#include <cstdint>
#include <cstddef>

#define CDIV(a,b) (((a)+(b)-1)/(b))
constexpr int NG = 64;
constexpr int CAP = 64;     // fixed in-edge capacity per node (Poisson(16): P(>64) ~ 1e-20)
constexpr int RBITS = 9;    // 512 nodes per dst-range
constexpr int NRMAX = 256;  // 196 ranges used at N=100k
constexpr int RCAP = 9216;  // per-range edge capacity (mean 8163, +11 sigma)

typedef _Float16 h4 __attribute__((ext_vector_type(4)));
typedef _Float16 h8 __attribute__((ext_vector_type(8)));
typedef float f4 __attribute__((ext_vector_type(4)));

__global__ void k_zero(int* p, long n) {
  long i = (long)blockIdx.x*blockDim.x + threadIdx.x;
  long stride = (long)gridDim.x*blockDim.x;
  for (; i < n; i += stride) p[i] = 0;
}

// phase 1: partition edges by dst-range; packed 4B records (dlocal<<17 | src), per-range regions
__global__ __launch_bounds__(256) void k_part(
    const int* __restrict__ src, const int* __restrict__ dst,
    int* __restrict__ rngcur, unsigned* __restrict__ part, int E) {
  __shared__ int hcnt[NRMAX], hbase[NRMAX], hfill[NRMAX];
  int tid = threadIdx.x;
  int base = blockIdx.x * 4096;
  hcnt[tid] = 0;
  __syncthreads();
  unsigned val[16]; int rr[16];
  #pragma unroll
  for (int u = 0; u < 16; u++) {
    int e = base + u*256 + tid;
    rr[u] = -1;
    if (e < E) {
      int s = src[e], d = dst[e];
      rr[u] = d >> RBITS;
      val[u] = ((unsigned)(d & ((1<<RBITS)-1)) << 17) | (unsigned)s;
      atomicAdd(&hcnt[rr[u]], 1);
    }
  }
  __syncthreads();
  hfill[tid] = 0;
  if (hcnt[tid]) hbase[tid] = atomicAdd(&rngcur[tid], hcnt[tid]);
  __syncthreads();
  #pragma unroll
  for (int u = 0; u < 16; u++) {
    if (rr[u] >= 0) {
      int p = hbase[rr[u]] + atomicAdd(&hfill[rr[u]], 1);
      if (p < RCAP) part[(size_t)rr[u]*RCAP + p] = val[u];
    }
  }
}

// phase 2: LDS counting-sort per range -> coalesced CSR row writes (exactly-once lines)
__global__ __launch_bounds__(512) void k_csr2(
    const unsigned* __restrict__ part, const int* __restrict__ rngcur,
    int* __restrict__ icnt, int* __restrict__ ecol, int N) {
  __shared__ unsigned sorted[RCAP];            // 36 KB
  __shared__ int lcnt[512], lpos[512], lcur[512];
  int r = blockIdx.x;
  int tid = threadIdx.x;
  int cnt = min(rngcur[r], RCAP);
  int n0 = r << RBITS;
  int nn = min(512, N - n0);
  const unsigned* p = part + (size_t)r * RCAP;
  lcnt[tid] = 0; lcur[tid] = 0;
  __syncthreads();
  // pass 1: count per dst-local
  for (int i = tid; i < cnt; i += 512)
    atomicAdd(&lcnt[p[i] >> 17], 1);
  __syncthreads();
  // inclusive scan (lpos); exclusive base = lpos - lcnt
  lpos[tid] = lcnt[tid];
  __syncthreads();
  for (int d = 1; d < 512; d <<= 1) {
    int t = (tid >= d) ? lpos[tid-d] : 0;
    __syncthreads();
    lpos[tid] += t;
    __syncthreads();
  }
  // pass 2: place src into sorted LDS at exact CSR-local position
  for (int i = tid; i < cnt; i += 512) {
    unsigned v = p[i];
    int d = v >> 17;
    int q = (lpos[d] - lcnt[d]) + atomicAdd(&lcur[d], 1);
    sorted[q] = v & 131071u;
  }
  __syncthreads();
  // coalesced icnt store
  if (tid < nn) icnt[n0 + tid] = min(lcnt[tid], CAP);
  // write-out: one wave per node, contiguous <=256B burst
  int wv = tid >> 6, lane = tid & 63;
  for (int i = wv; i < nn; i += 8) {
    int c = min(lcnt[i], CAP);
    if (lane < c)
      ecol[(size_t)(n0 + i)*CAP + lane] = (int)sorted[lpos[i] - lcnt[i] + lane];
  }
}

// per-node: dinv = rsqrt(deg) with deg = c+1 (incl self), graph histogram
__global__ void k_node2(const int* __restrict__ icnt, const int* __restrict__ batch,
                        float* __restrict__ dinv, int* __restrict__ cnt_g, int n) {
  __shared__ int hist[NG];
  int tid = threadIdx.x;
  int i = blockIdx.x*256 + tid;
  if (tid < NG) hist[tid] = 0;
  __syncthreads();
  if (i < n) {
    dinv[i] = rsqrtf((float)(icnt[i] + 1));
    atomicAdd(&hist[batch[i]], 1);
  }
  __syncthreads();
  if (tid < NG && hist[tid]) atomicAdd(&cnt_g[tid], hist[tid]);
}

// W[K x nout] fp32 -> WT[nout x K] fp16
__global__ void k_wcvt(const float* __restrict__ W, _Float16* __restrict__ WT,
                       int K, int nout) {
  int idx = blockIdx.x*256 + threadIdx.x;
  if (idx >= K*nout) return;
  int c = idx / K, k = idx % K;
  WT[idx] = (_Float16)W[(size_t)k*nout + c];
}

// unweighted gather on premultiplied features: out[i] = dinv[i]*(sum_e y[s_e] + y[i])
// L1: out = dinv*relu(dinv*sum + bias)
template<int F, bool L1>
__global__ __launch_bounds__(256) void k_gather_x(
    const _Float16* __restrict__ y, _Float16* __restrict__ z,
    const int* __restrict__ ecol, const int* __restrict__ icnt,
    const float* __restrict__ dinv, const float* __restrict__ bias, int n) {
  constexpr int LPN = F / 4;
  constexpr int NPW = 64 / LPN;
  int wid = (int)((blockIdx.x*(size_t)blockDim.x + threadIdx.x) >> 6);
  int lane = threadIdx.x & 63;
  int sub = lane / LPN;
  int li  = lane % LPN;
  int gw = wid * NPW + sub;
  if (gw >= n) return;
  float di = dinv[gw];
  h4 sv = *(const h4*)(y + (size_t)gw*F + li*4);
  float a0 = (float)sv.x, a1 = (float)sv.y, a2 = (float)sv.z, a3 = (float)sv.w;
  int cnt = icnt[gw];
  const int* col = ecol + (size_t)gw * CAP;
  int k = 0;
  for (; k + 7 < cnt; k += 8) {
    int c[8];
    #pragma unroll
    for (int u = 0; u < 8; u++) c[u] = col[k + u];
    #pragma unroll
    for (int u = 0; u < 8; u++) {
      h4 v = *(const h4*)(y + (size_t)c[u]*F + li*4);
      a0 += (float)v.x; a1 += (float)v.y; a2 += (float)v.z; a3 += (float)v.w;
    }
  }
  for (; k < cnt; k++) {
    h4 v = *(const h4*)(y + (size_t)col[k]*F + li*4);
    a0 += (float)v.x; a1 += (float)v.y; a2 += (float)v.z; a3 += (float)v.w;
  }
  if constexpr (L1) {
    a0 = di * fmaxf(di*a0 + bias[li*4+0], 0.f);
    a1 = di * fmaxf(di*a1 + bias[li*4+1], 0.f);
    a2 = di * fmaxf(di*a2 + bias[li*4+2], 0.f);
    a3 = di * fmaxf(di*a3 + bias[li*4+3], 0.f);
  } else {
    a0 *= di; a1 *= di; a2 *= di; a3 *= di;
  }
  h4 o; o.x = (_Float16)a0; o.y = (_Float16)a1; o.z = (_Float16)a2; o.w = (_Float16)a3;
  *(h4*)(z + (size_t)gw*F + li*4) = o;
}

// MFMA GEMM: C[n x NOUT] = A[n x K] @ W, NOUT = CF*64, block = 64 rows x NOUT.
// EPI: 0=store (x rowscale), 1=bias+relu (x rowscale) store, 2=bias+relu + fused graph pool
// AF32: A is fp32 (converted to fp16 during staging). rs: optional per-row scale (dinv).
template<int K, int CF, int EPI, bool AF32>
__global__ __launch_bounds__(256, 2) void k_mgemm(
    const void* __restrict__ Av, const _Float16* __restrict__ WT,
    const float* __restrict__ bias, _Float16* __restrict__ C,
    int n, const int* __restrict__ batch, float* __restrict__ gsum,
    const float* __restrict__ rs) {
  constexpr int KS = K / 32;
  constexpr int NOUT = CF * 64;
  constexpr int LDA = K + 8;
  __shared__ __align__(16) _Float16 sA[64][LDA];
  __shared__ float red[4][256];
  __shared__ int sBatch[64];
  int tid = threadIdx.x;
  int row0 = blockIdx.x * 64;
  int lane = tid & 63, wv = tid >> 6;
  int grp = lane >> 4, l16 = lane & 15;
  int wcol0 = wv * (CF * 16);

  {
    int srow = tid >> 2;
    bool ok = (row0 + srow) < n;
    if constexpr (AF32) {
      const float* A = (const float*)Av;
      #pragma unroll
      for (int u = 0; u < K/16; u++) {
        int c4 = (tid & 3) + 4*u;
        float4 v = ok ? *(const float4*)(A + (size_t)(row0+srow)*K + c4*4)
                      : make_float4(0.f,0.f,0.f,0.f);
        h4 o; o.x=(_Float16)v.x; o.y=(_Float16)v.y; o.z=(_Float16)v.z; o.w=(_Float16)v.w;
        *(h4*)&sA[srow][c4*4] = o;
      }
    } else {
      const _Float16* A = (const _Float16*)Av;
      #pragma unroll
      for (int u = 0; u < K/32; u++) {
        int c8 = (tid & 3) + 4*u;
        h8 v = {};
        if (ok) v = *(const h8*)(A + (size_t)(row0+srow)*K + c8*8);
        *(h8*)&sA[srow][c8*8] = v;
      }
    }
  }
  if constexpr (EPI == 2) {
    if (tid < 64) sBatch[tid] = (row0 + tid < n) ? batch[row0 + tid] : -1;
  }

  h8 bfrag[KS][CF];
  #pragma unroll
  for (int ks = 0; ks < KS; ks++)
    #pragma unroll
    for (int cf = 0; cf < CF; cf++) {
      int col = wcol0 + cf*16 + l16;
      bfrag[ks][cf] = *(const h8*)(WT + (size_t)col*K + ks*32 + grp*8);
    }

  f4 acc[4][CF] = {};
  __syncthreads();

  #pragma unroll
  for (int ks = 0; ks < KS; ks++) {
    h8 af[4];
    #pragma unroll
    for (int rf = 0; rf < 4; rf++)
      af[rf] = *(const h8*)&sA[rf*16 + l16][ks*32 + grp*8];
    #pragma unroll
    for (int rf = 0; rf < 4; rf++)
      #pragma unroll
      for (int cf = 0; cf < CF; cf++)
        acc[rf][cf] = __builtin_amdgcn_mfma_f32_16x16x32_f16(
            af[rf], bfrag[ks][cf], acc[rf][cf], 0, 0, 0);
  }

  if constexpr (EPI <= 1) {
    #pragma unroll
    for (int rf = 0; rf < 4; rf++) {
      #pragma unroll
      for (int r = 0; r < 4; r++) {
        int row = row0 + rf*16 + grp*4 + r;
        if (row < n) {
          float rsv = rs ? rs[row] : 1.f;
          #pragma unroll
          for (int cf = 0; cf < CF; cf++) {
            int col = wcol0 + cf*16 + l16;
            float v = acc[rf][cf][r];
            if constexpr (EPI == 1) v = fmaxf(v + bias[col], 0.f);
            v *= rsv;
            C[(size_t)row*NOUT + col] = (_Float16)v;
          }
        }
      }
    }
  } else {
    float bv[CF];
    #pragma unroll
    for (int cf = 0; cf < CF; cf++) bv[cf] = bias[wcol0 + cf*16 + l16];
    #pragma unroll
    for (int rf = 0; rf < 4; rf++)
      #pragma unroll
      for (int cf = 0; cf < CF; cf++)
        #pragma unroll
        for (int r = 0; r < 4; r++)
          acc[rf][cf][r] = fmaxf(acc[rf][cf][r] + bv[cf], 0.f);
    __syncthreads();
    int g0 = sBatch[0];
    int g1 = batch[min(row0 + 63, n - 1)];
    for (int g = g0; g <= g1; ++g) {
      float p[CF] = {};
      #pragma unroll
      for (int rf = 0; rf < 4; rf++)
        #pragma unroll
        for (int r = 0; r < 4; r++) {
          int lrow = rf*16 + grp*4 + r;
          bool m = (sBatch[lrow] == g);
          #pragma unroll
          for (int cf = 0; cf < CF; cf++)
            if (m) p[cf] += acc[rf][cf][r];
        }
      #pragma unroll
      for (int cf = 0; cf < CF; cf++)
        red[grp][wcol0 + cf*16 + l16] = p[cf];
      __syncthreads();
      if (tid < NOUT) {
        float s = red[0][tid] + red[1][tid] + red[2][tid] + red[3][tid];
        atomicAdd(&gsum[g*256 + tid], s);
      }
      __syncthreads();
    }
  }
}

__device__ __forceinline__ float sigm(float x) { return 1.f / (1.f + expf(-x)); }

// gates[g][j] for j in [0,1024): [0,512)=forward, [512,1024)=backward.
__global__ __launch_bounds__(256) void k_gates(
    const float* __restrict__ gsum, const int* __restrict__ cnt_g,
    const float* __restrict__ wf, const float* __restrict__ bf,
    const float* __restrict__ wb, const float* __restrict__ bb,
    float* __restrict__ gates) {
  int g = blockIdx.y;
  int j0 = blockIdx.x * 64;
  int tid = threadIdx.x;
  __shared__ float pooled[256];
  float invc = 1.0f / fmaxf((float)cnt_g[g], 1.0f);
  pooled[tid] = gsum[g*256 + tid] * invc;
  __syncthreads();
  int jl = tid >> 2, ks = tid & 3;
  int j = j0 + jl;
  const float* wrow;
  float bias;
  if (j < 512) { wrow = wf + (size_t)j*256;        bias = bf[j]; }
  else         { wrow = wb + (size_t)(j-512)*256;  bias = bb[j-512]; }
  const float4* w4 = (const float4*)(wrow + ks*64);
  const float4* p4 = (const float4*)(&pooled[ks*64]);
  float acc = 0.f;
  #pragma unroll
  for (int i = 0; i < 16; i++) {
    float4 a = w4[i], b = p4[i];
    acc += a.x*b.x + a.y*b.y + a.z*b.z + a.w*b.w;
  }
  acc += __shfl_xor(acc, 1, 64);
  acc += __shfl_xor(acc, 2, 64);
  if (ks == 0) gates[(size_t)g*1024 + j] = acc + bias;
}

// LSTM nonlinearity (T=1, zero state) + FC strip of 125 columns.
__global__ __launch_bounds__(256) void k_lstmfc(
    const float* __restrict__ gates, const float* __restrict__ fw,
    const float* __restrict__ fb, float* __restrict__ logits) {
  int g = blockIdx.y;
  int c0 = blockIdx.x * 125;
  int tid = threadIdx.x;
  __shared__ float gg[1024];
  __shared__ float lstm[256];
  __shared__ float sred[256];
  #pragma unroll
  for (int u = 0; u < 4; u++) gg[tid + u*256] = gates[(size_t)g*1024 + tid + u*256];
  __syncthreads();
  if (tid < 128) {
    float i = gg[tid], z = gg[256+tid], o = gg[384+tid];
    float cc = sigm(i)*tanhf(z);
    lstm[tid] = sigm(o)*tanhf(cc);
  } else {
    int u = tid - 128;
    float i = gg[512+u], z = gg[768+u], o = gg[896+u];
    float cc = sigm(i)*tanhf(z);
    lstm[128+u] = sigm(o)*tanhf(cc);
  }
  __syncthreads();
  int kh = tid >> 7;
  int cl = tid & 127;
  float acc = 0.f;
  if (cl < 125) {
    const float* fcol = fw + (size_t)kh*128*500 + (c0 + cl);
    #pragma unroll 8
    for (int k = 0; k < 128; k++)
      acc += lstm[kh*128 + k] * fcol[(size_t)k*500];
  }
  sred[tid] = acc;
  __syncthreads();
  if (tid < 125)
    logits[(size_t)g*500 + c0 + tid] = sred[tid] + sred[tid+128] + fb[c0 + tid];
}

// log_softmax over 500 logits per graph
__global__ __launch_bounds__(256) void k_smax(
    const float* __restrict__ logits, float* __restrict__ out) {
  int g = blockIdx.x, tid = threadIdx.x;
  __shared__ float sred[256];
  float l0 = logits[(size_t)g*500 + tid];
  float l1 = (tid < 244) ? logits[(size_t)g*500 + 256 + tid] : -1e30f;
  float m = fmaxf(l0, l1);
  sred[tid] = m; __syncthreads();
  for (int d = 128; d > 0; d >>= 1) {
    if (tid < d) sred[tid] = fmaxf(sred[tid], sred[tid+d]);
    __syncthreads();
  }
  float mx = sred[0]; __syncthreads();
  float s = expf(l0 - mx) + ((tid < 244) ? expf(l1 - mx) : 0.f);
  sred[tid] = s; __syncthreads();
  for (int d = 128; d > 0; d >>= 1) {
    if (tid < d) sred[tid] += sred[tid+d];
    __syncthreads();
  }
  float lse = logf(sred[0]) + mx;
  out[(size_t)g*500 + tid] = l0 - lse;
  if (tid < 244) out[(size_t)g*500 + 256 + tid] = l1 - lse;
}

extern "C" void kernel_launch(void* const* d_in, const int* in_sizes, int n_in,
                              void* d_out, int out_size, void* d_ws, size_t ws_size,
                              hipStream_t stream) {
  const float* x     = (const float*)d_in[0];
  const int*   ei    = (const int*)d_in[1];
  const int*   batch = (const int*)d_in[2];
  const float* W1 = (const float*)d_in[3];  const float* b1 = (const float*)d_in[4];
  const float* W2 = (const float*)d_in[5];  const float* b2 = (const float*)d_in[6];
  const float* W3 = (const float*)d_in[7];  const float* b3 = (const float*)d_in[8];
  const float* wf = (const float*)d_in[9];  const float* bf = (const float*)d_in[11];
  const float* wb = (const float*)d_in[12]; const float* bb = (const float*)d_in[14];
  const float* fw = (const float*)d_in[15]; const float* fb = (const float*)d_in[16];
  int N = in_sizes[2];
  int E = in_sizes[1] / 2;
  const int* src = ei;
  const int* dst = ei + E;
  int NR = CDIV(N, 1 << RBITS);            // 196 ranges

  char* w = (char*)d_ws;
  auto alloc = [&](size_t bytes) { char* p = w; w += (bytes + 255) / 256 * 256; return p; };
  int*   cnt_g  = (int*)  alloc(NG*4);
  int*   rngcur = (int*)  alloc(NRMAX*4);
  float* gsum   = (float*)alloc(NG*256*4);
  char*  zero_end = w;
  int*   icnt  = (int*)  alloc((size_t)N*4);
  float* dinv  = (float*)alloc((size_t)N*4);
  unsigned* part = (unsigned*)alloc((size_t)NR*RCAP*4);
  int*   ecol  = (int*)  alloc((size_t)N*CAP*4);
  _Float16* B0h = (_Float16*)alloc((size_t)N*128*2);
  _Float16* B1h = (_Float16*)alloc((size_t)N*128*2);
  _Float16* WT1 = (_Float16*)alloc(128*64*2);
  _Float16* WT2 = (_Float16*)alloc(64*128*2);
  _Float16* WT3 = (_Float16*)alloc(128*256*2);
  float* gates  = (float*)alloc((size_t)NG*1024*4);
  float* logits = (float*)alloc((size_t)NG*500*4);

  long zwords = (zero_end - (char*)cnt_g) / 4;
  k_zero<<<64, 256, 0, stream>>>(cnt_g, zwords);
  k_part<<<CDIV(E,4096), 256, 0, stream>>>(src, dst, rngcur, part, E);
  k_csr2<<<NR, 512, 0, stream>>>(part, rngcur, icnt, ecol, N);
  k_node2<<<CDIV(N,256), 256, 0, stream>>>(icnt, batch, dinv, cnt_g, N);
  k_wcvt<<<CDIV(128*64,256), 256, 0, stream>>>(W1, WT1, 128, 64);
  k_wcvt<<<CDIV(64*128,256), 256, 0, stream>>>(W2, WT2, 64, 128);
  k_wcvt<<<CDIV(128*256,256), 256, 0, stream>>>(W3, WT3, 128, 256);

  // layer 1: y~1 = dinv*(x @ W1)   (MFMA fp32->fp16, rowscale fused)
  k_mgemm<128,1,0,true><<<CDIV(N,64), 256, 0, stream>>>(x, WT1, nullptr, B0h, N, nullptr, nullptr, dinv);
  // gather1: h~1 = dinv*relu(dinv*(sum + self) + b1)
  k_gather_x<64,true><<<CDIV(N,16), 256, 0, stream>>>(B0h, B1h, ecol, icnt, dinv, b1, N);
  // gather2: z2 = dinv*(sum + self)
  k_gather_x<64,false><<<CDIV(N,16), 256, 0, stream>>>(B1h, B0h, ecol, icnt, dinv, nullptr, N);
  // h~2 = dinv*relu(z2 @ W2 + b2)
  k_mgemm<64,2,1,false><<<CDIV(N,64), 256, 0, stream>>>(B0h, WT2, b2, B1h, N, nullptr, nullptr, dinv);
  // gather3: z3 = dinv*(sum + self)
  k_gather_x<128,false><<<CDIV(N,8), 256, 0, stream>>>(B1h, B0h, ecol, icnt, dinv, nullptr, N);
  // relu(z3 @ W3 + b3) + fused graph pooling
  k_mgemm<128,4,2,false><<<CDIV(N,64), 256, 0, stream>>>(B0h, WT3, b3, nullptr, N, batch, gsum, nullptr);
  // head
  k_gates<<<dim3(16, NG), 256, 0, stream>>>(gsum, cnt_g, wf, bf, wb, bb, gates);
  k_lstmfc<<<dim3(4, NG), 256, 0, stream>>>(gates, fw, fb, logits);
  k_smax<<<NG, 256, 0, stream>>>(logits, (float*)d_out);
}

// Round 12
// 262.445 us; speedup vs baseline: 1.2672x; 1.0245x over previous
//
#include <hip/hip_runtime.h>
#include <cstdint>
#include <cstddef>

#define CDIV(a,b) (((a)+(b)-1)/(b))
constexpr int NG = 64;
constexpr int CAP = 64;     // fixed in-edge capacity per node (Poisson(16): P(>64) ~ 1e-20)
constexpr int RBITS = 9;    // 512 nodes per dst-range
constexpr int NRMAX = 256;  // 196 ranges used at N=100k
constexpr int RCAP = 9216;  // per-range edge capacity (mean 8163, +11 sigma)

typedef _Float16 h4 __attribute__((ext_vector_type(4)));
typedef _Float16 h8 __attribute__((ext_vector_type(8)));
typedef float f4 __attribute__((ext_vector_type(4)));

__global__ void k_zero(int* p, long n) {
  long i = (long)blockIdx.x*blockDim.x + threadIdx.x;
  long stride = (long)gridDim.x*blockDim.x;
  for (; i < n; i += stride) p[i] = 0;
}

// zero the pad rows (row index N) of the fp16 feature buffers.
// B0h needs F=64 pad at [N*64,+64); B1h needs F=64 pad and F=128 pad at [N*128,+128).
__global__ void k_padzero(_Float16* B0h, _Float16* B1h, int N) {
  int t = threadIdx.x;
  if (t < 64)       B0h[(size_t)N*64 + t] = (_Float16)0.f;
  else if (t < 128) B1h[(size_t)N*64 + (t-64)] = (_Float16)0.f;
  else              B1h[(size_t)N*128 + (t-128)] = (_Float16)0.f;
}

// phase 1: partition edges by dst-range; packed 4B records (dlocal<<17 | src), per-range regions
__global__ __launch_bounds__(256) void k_part(
    const int* __restrict__ src, const int* __restrict__ dst,
    int* __restrict__ rngcur, unsigned* __restrict__ part, int E) {
  __shared__ int hcnt[NRMAX], hbase[NRMAX], hfill[NRMAX];
  int tid = threadIdx.x;
  int base = blockIdx.x * 4096;
  hcnt[tid] = 0;
  __syncthreads();
  unsigned val[16]; int rr[16];
  #pragma unroll
  for (int u = 0; u < 16; u++) {
    int e = base + u*256 + tid;
    rr[u] = -1;
    if (e < E) {
      int s = src[e], d = dst[e];
      rr[u] = d >> RBITS;
      val[u] = ((unsigned)(d & ((1<<RBITS)-1)) << 17) | (unsigned)s;
      atomicAdd(&hcnt[rr[u]], 1);
    }
  }
  __syncthreads();
  hfill[tid] = 0;
  if (hcnt[tid]) hbase[tid] = atomicAdd(&rngcur[tid], hcnt[tid]);
  __syncthreads();
  #pragma unroll
  for (int u = 0; u < 16; u++) {
    if (rr[u] >= 0) {
      int p = hbase[rr[u]] + atomicAdd(&hfill[rr[u]], 1);
      if (p < RCAP) part[(size_t)rr[u]*RCAP + p] = val[u];
    }
  }
}

// phase 2: LDS counting-sort per range -> coalesced CSR row writes.
// Rows padded to multiple of 16 with sentinel index N (zero pad row in feature buffers).
__global__ __launch_bounds__(512) void k_csr2(
    const unsigned* __restrict__ part, const int* __restrict__ rngcur,
    int* __restrict__ icnt, int* __restrict__ ecol, int N) {
  __shared__ unsigned sorted[RCAP];            // 36 KB
  __shared__ int lcnt[512], lpos[512], lcur[512];
  int r = blockIdx.x;
  int tid = threadIdx.x;
  int cnt = min(rngcur[r], RCAP);
  int n0 = r << RBITS;
  int nn = min(512, N - n0);
  const unsigned* p = part + (size_t)r * RCAP;
  lcnt[tid] = 0; lcur[tid] = 0;
  __syncthreads();
  for (int i = tid; i < cnt; i += 512)
    atomicAdd(&lcnt[p[i] >> 17], 1);
  __syncthreads();
  lpos[tid] = lcnt[tid];
  __syncthreads();
  for (int d = 1; d < 512; d <<= 1) {
    int t = (tid >= d) ? lpos[tid-d] : 0;
    __syncthreads();
    lpos[tid] += t;
    __syncthreads();
  }
  for (int i = tid; i < cnt; i += 512) {
    unsigned v = p[i];
    int d = v >> 17;
    int q = (lpos[d] - lcnt[d]) + atomicAdd(&lcur[d], 1);
    sorted[q] = v & 131071u;
  }
  __syncthreads();
  if (tid < nn) icnt[n0 + tid] = min(lcnt[tid], CAP);
  // write-out: one wave per node; pad row to multiple of 16 with sentinel N
  int wv = tid >> 6, lane = tid & 63;
  for (int i = wv; i < nn; i += 8) {
    int c = min(lcnt[i], CAP);
    int pc = (c + 15) & ~15;
    if (lane < pc) {
      int v = (lane < c) ? (int)sorted[lpos[i] - lcnt[i] + lane] : N;
      ecol[(size_t)(n0 + i)*CAP + lane] = v;
    }
  }
}

// per-node: dinv = rsqrt(deg) with deg = c+1 (incl self), graph histogram
__global__ void k_node2(const int* __restrict__ icnt, const int* __restrict__ batch,
                        float* __restrict__ dinv, int* __restrict__ cnt_g, int n) {
  __shared__ int hist[NG];
  int tid = threadIdx.x;
  int i = blockIdx.x*256 + tid;
  if (tid < NG) hist[tid] = 0;
  __syncthreads();
  if (i < n) {
    dinv[i] = rsqrtf((float)(icnt[i] + 1));
    atomicAdd(&hist[batch[i]], 1);
  }
  __syncthreads();
  if (tid < NG && hist[tid]) atomicAdd(&cnt_g[tid], hist[tid]);
}

// W[K x nout] fp32 -> WT[nout x K] fp16
__global__ void k_wcvt(const float* __restrict__ W, _Float16* __restrict__ WT,
                       int K, int nout) {
  int idx = blockIdx.x*256 + threadIdx.x;
  if (idx >= K*nout) return;
  int c = idx / K, k = idx % K;
  WT[idx] = (_Float16)W[(size_t)k*nout + c];
}

// unweighted gather on premultiplied features: out[i] = dinv[i]*(sum_e y[s_e] + y[i])
// Rows padded to x16 with sentinel N -> tail-free 16-deep load batches.
template<int F, bool L1>
__global__ __launch_bounds__(256) void k_gather_x(
    const _Float16* __restrict__ y, _Float16* __restrict__ z,
    const int* __restrict__ ecol, const int* __restrict__ icnt,
    const float* __restrict__ dinv, const float* __restrict__ bias, int n) {
  constexpr int LPN = F / 4;
  constexpr int NPW = 64 / LPN;
  int wid = (int)((blockIdx.x*(size_t)blockDim.x + threadIdx.x) >> 6);
  int lane = threadIdx.x & 63;
  int sub = lane / LPN;
  int li  = lane % LPN;
  int gw = wid * NPW + sub;
  if (gw >= n) return;
  float di = dinv[gw];
  h4 sv = *(const h4*)(y + (size_t)gw*F + li*4);
  float a0 = (float)sv.x, a1 = (float)sv.y, a2 = (float)sv.z, a3 = (float)sv.w;
  int padc = (icnt[gw] + 15) & ~15;
  const int* col = ecol + (size_t)gw * CAP;
  for (int k = 0; k < padc; k += 16) {
    int4 c0 = *(const int4*)&col[k];
    int4 c1 = *(const int4*)&col[k+4];
    int4 c2 = *(const int4*)&col[k+8];
    int4 c3 = *(const int4*)&col[k+12];
    int c[16] = {c0.x,c0.y,c0.z,c0.w, c1.x,c1.y,c1.z,c1.w,
                 c2.x,c2.y,c2.z,c2.w, c3.x,c3.y,c3.z,c3.w};
    #pragma unroll
    for (int u = 0; u < 16; u++) {
      h4 v = *(const h4*)(y + (size_t)c[u]*F + li*4);
      a0 += (float)v.x; a1 += (float)v.y; a2 += (float)v.z; a3 += (float)v.w;
    }
  }
  if constexpr (L1) {
    a0 = di * fmaxf(di*a0 + bias[li*4+0], 0.f);
    a1 = di * fmaxf(di*a1 + bias[li*4+1], 0.f);
    a2 = di * fmaxf(di*a2 + bias[li*4+2], 0.f);
    a3 = di * fmaxf(di*a3 + bias[li*4+3], 0.f);
  } else {
    a0 *= di; a1 *= di; a2 *= di; a3 *= di;
  }
  h4 o; o.x = (_Float16)a0; o.y = (_Float16)a1; o.z = (_Float16)a2; o.w = (_Float16)a3;
  *(h4*)(z + (size_t)gw*F + li*4) = o;
}

// MFMA GEMM: C[n x NOUT] = A[n x K] @ W, NOUT = CF*64, block = 64 rows x NOUT.
// EPI: 0=store (x rowscale), 1=bias+relu (x rowscale) store, 2=bias+relu + fused graph pool
// AF32: A is fp32 (converted to fp16 during staging). rs: optional per-row scale (dinv).
template<int K, int CF, int EPI, bool AF32>
__global__ __launch_bounds__(256, 2) void k_mgemm(
    const void* __restrict__ Av, const _Float16* __restrict__ WT,
    const float* __restrict__ bias, _Float16* __restrict__ C,
    int n, const int* __restrict__ batch, float* __restrict__ gsum,
    const float* __restrict__ rs) {
  constexpr int KS = K / 32;
  constexpr int NOUT = CF * 64;
  constexpr int LDA = K + 8;
  __shared__ __align__(16) _Float16 sA[64][LDA];
  __shared__ float red[4][256];
  __shared__ int sBatch[64];
  int tid = threadIdx.x;
  int row0 = blockIdx.x * 64;
  int lane = tid & 63, wv = tid >> 6;
  int grp = lane >> 4, l16 = lane & 15;
  int wcol0 = wv * (CF * 16);

  {
    int srow = tid >> 2;
    bool ok = (row0 + srow) < n;
    if constexpr (AF32) {
      const float* A = (const float*)Av;
      #pragma unroll
      for (int u = 0; u < K/16; u++) {
        int c4 = (tid & 3) + 4*u;
        float4 v = ok ? *(const float4*)(A + (size_t)(row0+srow)*K + c4*4)
                      : make_float4(0.f,0.f,0.f,0.f);
        h4 o; o.x=(_Float16)v.x; o.y=(_Float16)v.y; o.z=(_Float16)v.z; o.w=(_Float16)v.w;
        *(h4*)&sA[srow][c4*4] = o;
      }
    } else {
      const _Float16* A = (const _Float16*)Av;
      #pragma unroll
      for (int u = 0; u < K/32; u++) {
        int c8 = (tid & 3) + 4*u;
        h8 v = {};
        if (ok) v = *(const h8*)(A + (size_t)(row0+srow)*K + c8*8);
        *(h8*)&sA[srow][c8*8] = v;
      }
    }
  }
  if constexpr (EPI == 2) {
    if (tid < 64) sBatch[tid] = (row0 + tid < n) ? batch[row0 + tid] : -1;
  }

  h8 bfrag[KS][CF];
  #pragma unroll
  for (int ks = 0; ks < KS; ks++)
    #pragma unroll
    for (int cf = 0; cf < CF; cf++) {
      int col = wcol0 + cf*16 + l16;
      bfrag[ks][cf] = *(const h8*)(WT + (size_t)col*K + ks*32 + grp*8);
    }

  f4 acc[4][CF] = {};
  __syncthreads();

  #pragma unroll
  for (int ks = 0; ks < KS; ks++) {
    h8 af[4];
    #pragma unroll
    for (int rf = 0; rf < 4; rf++)
      af[rf] = *(const h8*)&sA[rf*16 + l16][ks*32 + grp*8];
    #pragma unroll
    for (int rf = 0; rf < 4; rf++)
      #pragma unroll
      for (int cf = 0; cf < CF; cf++)
        acc[rf][cf] = __builtin_amdgcn_mfma_f32_16x16x32_f16(
            af[rf], bfrag[ks][cf], acc[rf][cf], 0, 0, 0);
  }

  if constexpr (EPI <= 1) {
    #pragma unroll
    for (int rf = 0; rf < 4; rf++) {
      #pragma unroll
      for (int r = 0; r < 4; r++) {
        int row = row0 + rf*16 + grp*4 + r;
        if (row < n) {
          float rsv = rs ? rs[row] : 1.f;
          #pragma unroll
          for (int cf = 0; cf < CF; cf++) {
            int col = wcol0 + cf*16 + l16;
            float v = acc[rf][cf][r];
            if constexpr (EPI == 1) v = fmaxf(v + bias[col], 0.f);
            v *= rsv;
            C[(size_t)row*NOUT + col] = (_Float16)v;
          }
        }
      }
    }
  } else {
    float bv[CF];
    #pragma unroll
    for (int cf = 0; cf < CF; cf++) bv[cf] = bias[wcol0 + cf*16 + l16];
    #pragma unroll
    for (int rf = 0; rf < 4; rf++)
      #pragma unroll
      for (int cf = 0; cf < CF; cf++)
        #pragma unroll
        for (int r = 0; r < 4; r++)
          acc[rf][cf][r] = fmaxf(acc[rf][cf][r] + bv[cf], 0.f);
    __syncthreads();
    int g0 = sBatch[0];
    int g1 = batch[min(row0 + 63, n - 1)];
    for (int g = g0; g <= g1; ++g) {
      float p[CF] = {};
      #pragma unroll
      for (int rf = 0; rf < 4; rf++)
        #pragma unroll
        for (int r = 0; r < 4; r++) {
          int lrow = rf*16 + grp*4 + r;
          bool m = (sBatch[lrow] == g);
          #pragma unroll
          for (int cf = 0; cf < CF; cf++)
            if (m) p[cf] += acc[rf][cf][r];
        }
      #pragma unroll
      for (int cf = 0; cf < CF; cf++)
        red[grp][wcol0 + cf*16 + l16] = p[cf];
      __syncthreads();
      if (tid < NOUT) {
        float s = red[0][tid] + red[1][tid] + red[2][tid] + red[3][tid];
        atomicAdd(&gsum[g*256 + tid], s);
      }
      __syncthreads();
    }
  }
}

__device__ __forceinline__ float sigm(float x) { return 1.f / (1.f + expf(-x)); }

// gates[g][j] for j in [0,1024): [0,512)=forward, [512,1024)=backward.
__global__ __launch_bounds__(256) void k_gates(
    const float* __restrict__ gsum, const int* __restrict__ cnt_g,
    const float* __restrict__ wf, const float* __restrict__ bf,
    const float* __restrict__ wb, const float* __restrict__ bb,
    float* __restrict__ gates) {
  int g = blockIdx.y;
  int j0 = blockIdx.x * 64;
  int tid = threadIdx.x;
  __shared__ float pooled[256];
  float invc = 1.0f / fmaxf((float)cnt_g[g], 1.0f);
  pooled[tid] = gsum[g*256 + tid] * invc;
  __syncthreads();
  int jl = tid >> 2, ks = tid & 3;
  int j = j0 + jl;
  const float* wrow;
  float bias;
  if (j < 512) { wrow = wf + (size_t)j*256;        bias = bf[j]; }
  else         { wrow = wb + (size_t)(j-512)*256;  bias = bb[j-512]; }
  const float4* w4 = (const float4*)(wrow + ks*64);
  const float4* p4 = (const float4*)(&pooled[ks*64]);
  float acc = 0.f;
  #pragma unroll
  for (int i = 0; i < 16; i++) {
    float4 a = w4[i], b = p4[i];
    acc += a.x*b.x + a.y*b.y + a.z*b.z + a.w*b.w;
  }
  acc += __shfl_xor(acc, 1, 64);
  acc += __shfl_xor(acc, 2, 64);
  if (ks == 0) gates[(size_t)g*1024 + j] = acc + bias;
}

// LSTM nonlinearity (T=1, zero state) + FC strip of 125 columns.
__global__ __launch_bounds__(256) void k_lstmfc(
    const float* __restrict__ gates, const float* __restrict__ fw,
    const float* __restrict__ fb, float* __restrict__ logits) {
  int g = blockIdx.y;
  int c0 = blockIdx.x * 125;
  int tid = threadIdx.x;
  __shared__ float gg[1024];
  __shared__ float lstm[256];
  __shared__ float sred[256];
  #pragma unroll
  for (int u = 0; u < 4; u++) gg[tid + u*256] = gates[(size_t)g*1024 + tid + u*256];
  __syncthreads();
  if (tid < 128) {
    float i = gg[tid], z = gg[256+tid], o = gg[384+tid];
    float cc = sigm(i)*tanhf(z);
    lstm[tid] = sigm(o)*tanhf(cc);
  } else {
    int u = tid - 128;
    float i = gg[512+u], z = gg[768+u], o = gg[896+u];
    float cc = sigm(i)*tanhf(z);
    lstm[128+u] = sigm(o)*tanhf(cc);
  }
  __syncthreads();
  int kh = tid >> 7;
  int cl = tid & 127;
  float acc = 0.f;
  if (cl < 125) {
    const float* fcol = fw + (size_t)kh*128*500 + (c0 + cl);
    #pragma unroll 8
    for (int k = 0; k < 128; k++)
      acc += lstm[kh*128 + k] * fcol[(size_t)k*500];
  }
  sred[tid] = acc;
  __syncthreads();
  if (tid < 125)
    logits[(size_t)g*500 + c0 + tid] = sred[tid] + sred[tid+128] + fb[c0 + tid];
}

// log_softmax over 500 logits per graph
__global__ __launch_bounds__(256) void k_smax(
    const float* __restrict__ logits, float* __restrict__ out) {
  int g = blockIdx.x, tid = threadIdx.x;
  __shared__ float sred[256];
  float l0 = logits[(size_t)g*500 + tid];
  float l1 = (tid < 244) ? logits[(size_t)g*500 + 256 + tid] : -1e30f;
  float m = fmaxf(l0, l1);
  sred[tid] = m; __syncthreads();
  for (int d = 128; d > 0; d >>= 1) {
    if (tid < d) sred[tid] = fmaxf(sred[tid], sred[tid+d]);
    __syncthreads();
  }
  float mx = sred[0]; __syncthreads();
  float s = expf(l0 - mx) + ((tid < 244) ? expf(l1 - mx) : 0.f);
  sred[tid] = s; __syncthreads();
  for (int d = 128; d > 0; d >>= 1) {
    if (tid < d) sred[tid] += sred[tid+d];
    __syncthreads();
  }
  float lse = logf(sred[0]) + mx;
  out[(size_t)g*500 + tid] = l0 - lse;
  if (tid < 244) out[(size_t)g*500 + 256 + tid] = l1 - lse;
}

extern "C" void kernel_launch(void* const* d_in, const int* in_sizes, int n_in,
                              void* d_out, int out_size, void* d_ws, size_t ws_size,
                              hipStream_t stream) {
  const float* x     = (const float*)d_in[0];
  const int*   ei    = (const int*)d_in[1];
  const int*   batch = (const int*)d_in[2];
  const float* W1 = (const float*)d_in[3];  const float* b1 = (const float*)d_in[4];
  const float* W2 = (const float*)d_in[5];  const float* b2 = (const float*)d_in[6];
  const float* W3 = (const float*)d_in[7];  const float* b3 = (const float*)d_in[8];
  const float* wf = (const float*)d_in[9];  const float* bf = (const float*)d_in[11];
  const float* wb = (const float*)d_in[12]; const float* bb = (const float*)d_in[14];
  const float* fw = (const float*)d_in[15]; const float* fb = (const float*)d_in[16];
  int N = in_sizes[2];
  int E = in_sizes[1] / 2;
  const int* src = ei;
  const int* dst = ei + E;
  int NR = CDIV(N, 1 << RBITS);            // 196 ranges

  char* w = (char*)d_ws;
  auto alloc = [&](size_t bytes) { char* p = w; w += (bytes + 255) / 256 * 256; return p; };
  int*   cnt_g  = (int*)  alloc(NG*4);
  int*   rngcur = (int*)  alloc(NRMAX*4);
  float* gsum   = (float*)alloc(NG*256*4);
  char*  zero_end = w;
  int*   icnt  = (int*)  alloc((size_t)N*4);
  float* dinv  = (float*)alloc((size_t)N*4);
  unsigned* part = (unsigned*)alloc((size_t)NR*RCAP*4);
  int*   ecol  = (int*)  alloc((size_t)N*CAP*4);
  _Float16* B0h = (_Float16*)alloc(((size_t)N+1)*128*2);
  _Float16* B1h = (_Float16*)alloc(((size_t)N+1)*128*2);
  _Float16* WT1 = (_Float16*)alloc(128*64*2);
  _Float16* WT2 = (_Float16*)alloc(64*128*2);
  _Float16* WT3 = (_Float16*)alloc(128*256*2);
  float* gates  = (float*)alloc((size_t)NG*1024*4);
  float* logits = (float*)alloc((size_t)NG*500*4);

  long zwords = (zero_end - (char*)cnt_g) / 4;
  k_zero<<<64, 256, 0, stream>>>(cnt_g, zwords);
  k_padzero<<<1, 256, 0, stream>>>(B0h, B1h, N);
  k_part<<<CDIV(E,4096), 256, 0, stream>>>(src, dst, rngcur, part, E);
  k_csr2<<<NR, 512, 0, stream>>>(part, rngcur, icnt, ecol, N);
  k_node2<<<CDIV(N,256), 256, 0, stream>>>(icnt, batch, dinv, cnt_g, N);
  k_wcvt<<<CDIV(128*64,256), 256, 0, stream>>>(W1, WT1, 128, 64);
  k_wcvt<<<CDIV(64*128,256), 256, 0, stream>>>(W2, WT2, 64, 128);
  k_wcvt<<<CDIV(128*256,256), 256, 0, stream>>>(W3, WT3, 128, 256);

  // layer 1: y~1 = dinv*(x @ W1)   (MFMA fp32->fp16, rowscale fused)
  k_mgemm<128,1,0,true><<<CDIV(N,64), 256, 0, stream>>>(x, WT1, nullptr, B0h, N, nullptr, nullptr, dinv);
  // gather1: h~1 = dinv*relu(dinv*(sum + self) + b1)
  k_gather_x<64,true><<<CDIV(N,16), 256, 0, stream>>>(B0h, B1h, ecol, icnt, dinv, b1, N);
  // gather2: z2 = dinv*(sum + self)
  k_gather_x<64,false><<<CDIV(N,16), 256, 0, stream>>>(B1h, B0h, ecol, icnt, dinv, nullptr, N);
  // h~2 = dinv*relu(z2 @ W2 + b2)
  k_mgemm<64,2,1,false><<<CDIV(N,64), 256, 0, stream>>>(B0h, WT2, b2, B1h, N, nullptr, nullptr, dinv);
  // gather3: z3 = dinv*(sum + self)
  k_gather_x<128,false><<<CDIV(N,8), 256, 0, stream>>>(B1h, B0h, ecol, icnt, dinv, nullptr, N);
  // relu(z3 @ W3 + b3) + fused graph pooling
  k_mgemm<128,4,2,false><<<CDIV(N,64), 256, 0, stream>>>(B0h, WT3, b3, nullptr, N, batch, gsum, nullptr);
  // head
  k_gates<<<dim3(16, NG), 256, 0, stream>>>(gsum, cnt_g, wf, bf, wb, bb, gates);
  k_lstmfc<<<dim3(4, NG), 256, 0, stream>>>(gates, fw, fb, logits);
  k_smax<<<NG, 256, 0, stream>>>(logits, (float*)d_out);
}

// Round 13
// 211.794 us; speedup vs baseline: 1.5703x; 1.2392x over previous
//
#include <hip/hip_runtime.h>
#include <cstdint>
#include <cstddef>

#define CDIV(a,b) (((a)+(b)-1)/(b))
constexpr int NG = 64;
constexpr int CAP = 64;     // fixed in-edge capacity per node (Poisson(16): P(>64) ~ 1e-20)
constexpr int RBITS = 9;    // 512 nodes per dst-range
constexpr int NRMAX = 256;  // 196 ranges used at N=100k
constexpr int RCAP = 9216;  // per-range edge capacity (mean 8163, +11 sigma)

typedef _Float16 h4 __attribute__((ext_vector_type(4)));
typedef _Float16 h8 __attribute__((ext_vector_type(8)));
typedef float f4 __attribute__((ext_vector_type(4)));
typedef float f2 __attribute__((ext_vector_type(2)));

// fp8 e4m3 helpers (OCP on gfx950)
__device__ __forceinline__ void acc8(int2 v, float* a) {
  f2 p;
  p = __builtin_amdgcn_cvt_pk_f32_fp8(v.x, false); a[0] += p.x; a[1] += p.y;
  p = __builtin_amdgcn_cvt_pk_f32_fp8(v.x, true);  a[2] += p.x; a[3] += p.y;
  p = __builtin_amdgcn_cvt_pk_f32_fp8(v.y, false); a[4] += p.x; a[5] += p.y;
  p = __builtin_amdgcn_cvt_pk_f32_fp8(v.y, true);  a[6] += p.x; a[7] += p.y;
}
__device__ __forceinline__ int pack4(float x0, float x1, float x2, float x3) {
  int r = __builtin_amdgcn_cvt_pk_fp8_f32(x0, x1, 0, false);
  r = __builtin_amdgcn_cvt_pk_fp8_f32(x2, x3, r, true);
  return r;
}

__global__ void k_zero(int* p, long n) {
  long i = (long)blockIdx.x*blockDim.x + threadIdx.x;
  long stride = (long)gridDim.x*blockDim.x;
  for (; i < n; i += stride) p[i] = 0;
}

// zero the fp8 pad rows (row index N): Q0@F64, Q1@F64, Q1@F128
__global__ void k_padzero(unsigned char* Q0, unsigned char* Q1, int N) {
  int t = threadIdx.x;
  if (t < 64)       Q0[(size_t)N*64 + t] = 0;
  else if (t < 128) Q1[(size_t)N*64 + (t-64)] = 0;
  else              Q1[(size_t)N*128 + (t-128)] = 0;
}

// phase 1: partition edges by dst-range; packed 4B records (dlocal<<17 | src)
__global__ __launch_bounds__(256) void k_part(
    const int* __restrict__ src, const int* __restrict__ dst,
    int* __restrict__ rngcur, unsigned* __restrict__ part, int E) {
  __shared__ int hcnt[NRMAX], hbase[NRMAX], hfill[NRMAX];
  int tid = threadIdx.x;
  int base = blockIdx.x * 4096;
  hcnt[tid] = 0;
  __syncthreads();
  unsigned val[16]; int rr[16];
  #pragma unroll
  for (int u = 0; u < 16; u++) {
    int e = base + u*256 + tid;
    rr[u] = -1;
    if (e < E) {
      int s = src[e], d = dst[e];
      rr[u] = d >> RBITS;
      val[u] = ((unsigned)(d & ((1<<RBITS)-1)) << 17) | (unsigned)s;
      atomicAdd(&hcnt[rr[u]], 1);
    }
  }
  __syncthreads();
  hfill[tid] = 0;
  if (hcnt[tid]) hbase[tid] = atomicAdd(&rngcur[tid], hcnt[tid]);
  __syncthreads();
  #pragma unroll
  for (int u = 0; u < 16; u++) {
    if (rr[u] >= 0) {
      int p = hbase[rr[u]] + atomicAdd(&hfill[rr[u]], 1);
      if (p < RCAP) part[(size_t)rr[u]*RCAP + p] = val[u];
    }
  }
}

// phase 2: LDS counting-sort per range -> coalesced CSR row writes.
// Rows padded to multiple of 16 with sentinel index N (zero pad row in feature buffers).
__global__ __launch_bounds__(512) void k_csr2(
    const unsigned* __restrict__ part, const int* __restrict__ rngcur,
    int* __restrict__ icnt, int* __restrict__ ecol, int N) {
  __shared__ unsigned sorted[RCAP];
  __shared__ int lcnt[512], lpos[512], lcur[512];
  int r = blockIdx.x;
  int tid = threadIdx.x;
  int cnt = min(rngcur[r], RCAP);
  int n0 = r << RBITS;
  int nn = min(512, N - n0);
  const unsigned* p = part + (size_t)r * RCAP;
  lcnt[tid] = 0; lcur[tid] = 0;
  __syncthreads();
  for (int i = tid; i < cnt; i += 512)
    atomicAdd(&lcnt[p[i] >> 17], 1);
  __syncthreads();
  lpos[tid] = lcnt[tid];
  __syncthreads();
  for (int d = 1; d < 512; d <<= 1) {
    int t = (tid >= d) ? lpos[tid-d] : 0;
    __syncthreads();
    lpos[tid] += t;
    __syncthreads();
  }
  for (int i = tid; i < cnt; i += 512) {
    unsigned v = p[i];
    int d = v >> 17;
    int q = (lpos[d] - lcnt[d]) + atomicAdd(&lcur[d], 1);
    sorted[q] = v & 131071u;
  }
  __syncthreads();
  if (tid < nn) icnt[n0 + tid] = min(lcnt[tid], CAP);
  int wv = tid >> 6, lane = tid & 63;
  for (int i = wv; i < nn; i += 8) {
    int c = min(lcnt[i], CAP);
    int pc = (c + 15) & ~15;
    if (lane < pc) {
      int v = (lane < c) ? (int)sorted[lpos[i] - lcnt[i] + lane] : N;
      ecol[(size_t)(n0 + i)*CAP + lane] = v;
    }
  }
}

// per-node: dinv = rsqrt(deg) with deg = c+1 (incl self), graph histogram
__global__ void k_node2(const int* __restrict__ icnt, const int* __restrict__ batch,
                        float* __restrict__ dinv, int* __restrict__ cnt_g, int n) {
  __shared__ int hist[NG];
  int tid = threadIdx.x;
  int i = blockIdx.x*256 + tid;
  if (tid < NG) hist[tid] = 0;
  __syncthreads();
  if (i < n) {
    dinv[i] = rsqrtf((float)(icnt[i] + 1));
    atomicAdd(&hist[batch[i]], 1);
  }
  __syncthreads();
  if (tid < NG && hist[tid]) atomicAdd(&cnt_g[tid], hist[tid]);
}

// W[K x nout] fp32 -> WT[nout x K] fp16
__global__ void k_wcvt(const float* __restrict__ W, _Float16* __restrict__ WT,
                       int K, int nout) {
  int idx = blockIdx.x*256 + threadIdx.x;
  if (idx >= K*nout) return;
  int c = idx / K, k = idx % K;
  WT[idx] = (_Float16)W[(size_t)k*nout + c];
}

// fp8 gather on premultiplied features: out[i] = dinv[i]*(sum_e y[s_e] + y[i])
// 8 B/lane = 8 fp8 elems; F=128: 16 lanes/node (4 nodes/wave); F=64: 8 lanes/node (8/wave).
template<int F, bool L1>
__global__ __launch_bounds__(256) void k_gather_q(
    const unsigned char* __restrict__ y, unsigned char* __restrict__ z,
    const int* __restrict__ ecol, const int* __restrict__ icnt,
    const float* __restrict__ dinv, const float* __restrict__ bias, int n) {
  constexpr int LPN = F / 8;
  constexpr int NPW = 64 / LPN;
  int wid = (int)((blockIdx.x*(size_t)blockDim.x + threadIdx.x) >> 6);
  int lane = threadIdx.x & 63;
  int sub = lane / LPN;
  int li  = lane % LPN;
  int gw = wid * NPW + sub;
  if (gw >= n) return;
  float di = dinv[gw];
  float a[8] = {};
  { int2 v = *(const int2*)(y + (size_t)gw*F + li*8); acc8(v, a); }
  int padc = (icnt[gw] + 15) & ~15;
  const int* col = ecol + (size_t)gw * CAP;
  for (int k = 0; k < padc; k += 16) {
    int4 c0 = *(const int4*)&col[k];
    int4 c1 = *(const int4*)&col[k+4];
    int4 c2 = *(const int4*)&col[k+8];
    int4 c3 = *(const int4*)&col[k+12];
    int c[16] = {c0.x,c0.y,c0.z,c0.w, c1.x,c1.y,c1.z,c1.w,
                 c2.x,c2.y,c2.z,c2.w, c3.x,c3.y,c3.z,c3.w};
    int2 v[16];
    #pragma unroll
    for (int u = 0; u < 16; u++)
      v[u] = *(const int2*)(y + (size_t)c[u]*F + li*8);
    #pragma unroll
    for (int u = 0; u < 16; u++) acc8(v[u], a);
  }
  if constexpr (L1) {
    #pragma unroll
    for (int j = 0; j < 8; j++)
      a[j] = di * fmaxf(di*a[j] + bias[li*8 + j], 0.f);
  } else {
    #pragma unroll
    for (int j = 0; j < 8; j++) a[j] *= di;
  }
  int2 o;
  o.x = pack4(a[0], a[1], a[2], a[3]);
  o.y = pack4(a[4], a[5], a[6], a[7]);
  *(int2*)(z + (size_t)gw*F + li*8) = o;
}

// MFMA GEMM: C[n x NOUT] = A[n x K] @ W, NOUT = CF*64, block = 64 rows x NOUT.
// EPI: 0=store (x rowscale), 1=bias+relu (x rowscale) store, 2=bias+relu + fused graph pool
// AF32: A fp32 (layer 1); else A fp8. C stored fp8 (EPI<=1). rs: optional per-row scale.
template<int K, int CF, int EPI, bool AF32>
__global__ __launch_bounds__(256, 2) void k_mgemm(
    const void* __restrict__ Av, const _Float16* __restrict__ WT,
    const float* __restrict__ bias, unsigned char* __restrict__ C,
    int n, const int* __restrict__ batch, float* __restrict__ gsum,
    const float* __restrict__ rs) {
  constexpr int KS = K / 32;
  constexpr int NOUT = CF * 64;
  constexpr int LDA = K + 8;
  __shared__ __align__(16) _Float16 sA[64][LDA];
  __shared__ float red[4][256];
  __shared__ int sBatch[64];
  int tid = threadIdx.x;
  int row0 = blockIdx.x * 64;
  int lane = tid & 63, wv = tid >> 6;
  int grp = lane >> 4, l16 = lane & 15;
  int wcol0 = wv * (CF * 16);

  {
    int srow = tid >> 2;
    bool ok = (row0 + srow) < n;
    if constexpr (AF32) {
      const float* A = (const float*)Av;
      #pragma unroll
      for (int u = 0; u < K/16; u++) {
        int c4 = (tid & 3) + 4*u;
        float4 v = ok ? *(const float4*)(A + (size_t)(row0+srow)*K + c4*4)
                      : make_float4(0.f,0.f,0.f,0.f);
        h4 o; o.x=(_Float16)v.x; o.y=(_Float16)v.y; o.z=(_Float16)v.z; o.w=(_Float16)v.w;
        *(h4*)&sA[srow][c4*4] = o;
      }
    } else {
      const unsigned char* A = (const unsigned char*)Av;
      #pragma unroll
      for (int u = 0; u < K/32; u++) {
        int off = ((tid & 3) + 4*u) * 8;
        int2 v = ok ? *(const int2*)(A + (size_t)(row0+srow)*K + off) : make_int2(0,0);
        f2 p0 = __builtin_amdgcn_cvt_pk_f32_fp8(v.x, false);
        f2 p1 = __builtin_amdgcn_cvt_pk_f32_fp8(v.x, true);
        f2 p2 = __builtin_amdgcn_cvt_pk_f32_fp8(v.y, false);
        f2 p3 = __builtin_amdgcn_cvt_pk_f32_fp8(v.y, true);
        h8 o;
        o[0]=(_Float16)p0.x; o[1]=(_Float16)p0.y; o[2]=(_Float16)p1.x; o[3]=(_Float16)p1.y;
        o[4]=(_Float16)p2.x; o[5]=(_Float16)p2.y; o[6]=(_Float16)p3.x; o[7]=(_Float16)p3.y;
        *(h8*)&sA[srow][off] = o;
      }
    }
  }
  if constexpr (EPI == 2) {
    if (tid < 64) sBatch[tid] = (row0 + tid < n) ? batch[row0 + tid] : -1;
  }

  h8 bfrag[KS][CF];
  #pragma unroll
  for (int ks = 0; ks < KS; ks++)
    #pragma unroll
    for (int cf = 0; cf < CF; cf++) {
      int col = wcol0 + cf*16 + l16;
      bfrag[ks][cf] = *(const h8*)(WT + (size_t)col*K + ks*32 + grp*8);
    }

  f4 acc[4][CF] = {};
  __syncthreads();

  #pragma unroll
  for (int ks = 0; ks < KS; ks++) {
    h8 af[4];
    #pragma unroll
    for (int rf = 0; rf < 4; rf++)
      af[rf] = *(const h8*)&sA[rf*16 + l16][ks*32 + grp*8];
    #pragma unroll
    for (int rf = 0; rf < 4; rf++)
      #pragma unroll
      for (int cf = 0; cf < CF; cf++)
        acc[rf][cf] = __builtin_amdgcn_mfma_f32_16x16x32_f16(
            af[rf], bfrag[ks][cf], acc[rf][cf], 0, 0, 0);
  }

  if constexpr (EPI <= 1) {
    #pragma unroll
    for (int rf = 0; rf < 4; rf++) {
      #pragma unroll
      for (int r = 0; r < 4; r++) {
        int row = row0 + rf*16 + grp*4 + r;
        if (row < n) {
          float rsv = rs ? rs[row] : 1.f;
          #pragma unroll
          for (int cf = 0; cf < CF; cf++) {
            int col = wcol0 + cf*16 + l16;
            float v = acc[rf][cf][r];
            if constexpr (EPI == 1) v = fmaxf(v + bias[col], 0.f);
            v *= rsv;
            int b = __builtin_amdgcn_cvt_pk_fp8_f32(v, v, 0, false);
            C[(size_t)row*NOUT + col] = (unsigned char)(b & 0xff);
          }
        }
      }
    }
  } else {
    float bv[CF];
    #pragma unroll
    for (int cf = 0; cf < CF; cf++) bv[cf] = bias[wcol0 + cf*16 + l16];
    #pragma unroll
    for (int rf = 0; rf < 4; rf++)
      #pragma unroll
      for (int cf = 0; cf < CF; cf++)
        #pragma unroll
        for (int r = 0; r < 4; r++)
          acc[rf][cf][r] = fmaxf(acc[rf][cf][r] + bv[cf], 0.f);
    __syncthreads();
    int g0 = sBatch[0];
    int g1 = batch[min(row0 + 63, n - 1)];
    for (int g = g0; g <= g1; ++g) {
      float p[CF] = {};
      #pragma unroll
      for (int rf = 0; rf < 4; rf++)
        #pragma unroll
        for (int r = 0; r < 4; r++) {
          int lrow = rf*16 + grp*4 + r;
          bool m = (sBatch[lrow] == g);
          #pragma unroll
          for (int cf = 0; cf < CF; cf++)
            if (m) p[cf] += acc[rf][cf][r];
        }
      #pragma unroll
      for (int cf = 0; cf < CF; cf++)
        red[grp][wcol0 + cf*16 + l16] = p[cf];
      __syncthreads();
      if (tid < NOUT) {
        float s = red[0][tid] + red[1][tid] + red[2][tid] + red[3][tid];
        atomicAdd(&gsum[g*256 + tid], s);
      }
      __syncthreads();
    }
  }
}

__device__ __forceinline__ float sigm(float x) { return 1.f / (1.f + expf(-x)); }

// gates[g][j] for j in [0,1024): [0,512)=forward, [512,1024)=backward.
__global__ __launch_bounds__(256) void k_gates(
    const float* __restrict__ gsum, const int* __restrict__ cnt_g,
    const float* __restrict__ wf, const float* __restrict__ bf,
    const float* __restrict__ wb, const float* __restrict__ bb,
    float* __restrict__ gates) {
  int g = blockIdx.y;
  int j0 = blockIdx.x * 64;
  int tid = threadIdx.x;
  __shared__ float pooled[256];
  float invc = 1.0f / fmaxf((float)cnt_g[g], 1.0f);
  pooled[tid] = gsum[g*256 + tid] * invc;
  __syncthreads();
  int jl = tid >> 2, ks = tid & 3;
  int j = j0 + jl;
  const float* wrow;
  float bias;
  if (j < 512) { wrow = wf + (size_t)j*256;        bias = bf[j]; }
  else         { wrow = wb + (size_t)(j-512)*256;  bias = bb[j-512]; }
  const float4* w4 = (const float4*)(wrow + ks*64);
  const float4* p4 = (const float4*)(&pooled[ks*64]);
  float acc = 0.f;
  #pragma unroll
  for (int i = 0; i < 16; i++) {
    float4 a = w4[i], b = p4[i];
    acc += a.x*b.x + a.y*b.y + a.z*b.z + a.w*b.w;
  }
  acc += __shfl_xor(acc, 1, 64);
  acc += __shfl_xor(acc, 2, 64);
  if (ks == 0) gates[(size_t)g*1024 + j] = acc + bias;
}

// LSTM nonlinearity (T=1, zero state) + FC strip of 125 columns.
__global__ __launch_bounds__(256) void k_lstmfc(
    const float* __restrict__ gates, const float* __restrict__ fw,
    const float* __restrict__ fb, float* __restrict__ logits) {
  int g = blockIdx.y;
  int c0 = blockIdx.x * 125;
  int tid = threadIdx.x;
  __shared__ float gg[1024];
  __shared__ float lstm[256];
  __shared__ float sred[256];
  #pragma unroll
  for (int u = 0; u < 4; u++) gg[tid + u*256] = gates[(size_t)g*1024 + tid + u*256];
  __syncthreads();
  if (tid < 128) {
    float i = gg[tid], z = gg[256+tid], o = gg[384+tid];
    float cc = sigm(i)*tanhf(z);
    lstm[tid] = sigm(o)*tanhf(cc);
  } else {
    int u = tid - 128;
    float i = gg[512+u], z = gg[768+u], o = gg[896+u];
    float cc = sigm(i)*tanhf(z);
    lstm[128+u] = sigm(o)*tanhf(cc);
  }
  __syncthreads();
  int kh = tid >> 7;
  int cl = tid & 127;
  float acc = 0.f;
  if (cl < 125) {
    const float* fcol = fw + (size_t)kh*128*500 + (c0 + cl);
    #pragma unroll 8
    for (int k = 0; k < 128; k++)
      acc += lstm[kh*128 + k] * fcol[(size_t)k*500];
  }
  sred[tid] = acc;
  __syncthreads();
  if (tid < 125)
    logits[(size_t)g*500 + c0 + tid] = sred[tid] + sred[tid+128] + fb[c0 + tid];
}

// log_softmax over 500 logits per graph
__global__ __launch_bounds__(256) void k_smax(
    const float* __restrict__ logits, float* __restrict__ out) {
  int g = blockIdx.x, tid = threadIdx.x;
  __shared__ float sred[256];
  float l0 = logits[(size_t)g*500 + tid];
  float l1 = (tid < 244) ? logits[(size_t)g*500 + 256 + tid] : -1e30f;
  float m = fmaxf(l0, l1);
  sred[tid] = m; __syncthreads();
  for (int d = 128; d > 0; d >>= 1) {
    if (tid < d) sred[tid] = fmaxf(sred[tid], sred[tid+d]);
    __syncthreads();
  }
  float mx = sred[0]; __syncthreads();
  float s = expf(l0 - mx) + ((tid < 244) ? expf(l1 - mx) : 0.f);
  sred[tid] = s; __syncthreads();
  for (int d = 128; d > 0; d >>= 1) {
    if (tid < d) sred[tid] += sred[tid+d];
    __syncthreads();
  }
  float lse = logf(sred[0]) + mx;
  out[(size_t)g*500 + tid] = l0 - lse;
  if (tid < 244) out[(size_t)g*500 + 256 + tid] = l1 - lse;
}

extern "C" void kernel_launch(void* const* d_in, const int* in_sizes, int n_in,
                              void* d_out, int out_size, void* d_ws, size_t ws_size,
                              hipStream_t stream) {
  const float* x     = (const float*)d_in[0];
  const int*   ei    = (const int*)d_in[1];
  const int*   batch = (const int*)d_in[2];
  const float* W1 = (const float*)d_in[3];  const float* b1 = (const float*)d_in[4];
  const float* W2 = (const float*)d_in[5];  const float* b2 = (const float*)d_in[6];
  const float* W3 = (const float*)d_in[7];  const float* b3 = (const float*)d_in[8];
  const float* wf = (const float*)d_in[9];  const float* bf = (const float*)d_in[11];
  const float* wb = (const float*)d_in[12]; const float* bb = (const float*)d_in[14];
  const float* fw = (const float*)d_in[15]; const float* fb = (const float*)d_in[16];
  int N = in_sizes[2];
  int E = in_sizes[1] / 2;
  const int* src = ei;
  const int* dst = ei + E;
  int NR = CDIV(N, 1 << RBITS);            // 196 ranges

  char* w = (char*)d_ws;
  auto alloc = [&](size_t bytes) { char* p = w; w += (bytes + 255) / 256 * 256; return p; };
  int*   cnt_g  = (int*)  alloc(NG*4);
  int*   rngcur = (int*)  alloc(NRMAX*4);
  float* gsum   = (float*)alloc(NG*256*4);
  char*  zero_end = w;
  int*   icnt  = (int*)  alloc((size_t)N*4);
  float* dinv  = (float*)alloc((size_t)N*4);
  unsigned* part = (unsigned*)alloc((size_t)NR*RCAP*4);
  int*   ecol  = (int*)  alloc((size_t)N*CAP*4);
  unsigned char* Q0 = (unsigned char*)alloc(((size_t)N+1)*128);
  unsigned char* Q1 = (unsigned char*)alloc(((size_t)N+1)*128);
  _Float16* WT1 = (_Float16*)alloc(128*64*2);
  _Float16* WT2 = (_Float16*)alloc(64*128*2);
  _Float16* WT3 = (_Float16*)alloc(128*256*2);
  float* gates  = (float*)alloc((size_t)NG*1024*4);
  float* logits = (float*)alloc((size_t)NG*500*4);

  long zwords = (zero_end - (char*)cnt_g) / 4;
  k_zero<<<64, 256, 0, stream>>>(cnt_g, zwords);
  k_padzero<<<1, 256, 0, stream>>>(Q0, Q1, N);
  k_part<<<CDIV(E,4096), 256, 0, stream>>>(src, dst, rngcur, part, E);
  k_csr2<<<NR, 512, 0, stream>>>(part, rngcur, icnt, ecol, N);
  k_node2<<<CDIV(N,256), 256, 0, stream>>>(icnt, batch, dinv, cnt_g, N);
  k_wcvt<<<CDIV(128*64,256), 256, 0, stream>>>(W1, WT1, 128, 64);
  k_wcvt<<<CDIV(64*128,256), 256, 0, stream>>>(W2, WT2, 64, 128);
  k_wcvt<<<CDIV(128*256,256), 256, 0, stream>>>(W3, WT3, 128, 256);

  // layer 1: y~1 = dinv*(x @ W1)  (MFMA fp32->fp16, fp8 store, rowscale fused)
  k_mgemm<128,1,0,true><<<CDIV(N,64), 256, 0, stream>>>(x, WT1, nullptr, Q0, N, nullptr, nullptr, dinv);
  // gather1: h~1 = dinv*relu(dinv*(sum + self) + b1)
  k_gather_q<64,true><<<CDIV(N,32), 256, 0, stream>>>(Q0, Q1, ecol, icnt, dinv, b1, N);
  // gather2: z2 = dinv*(sum + self)
  k_gather_q<64,false><<<CDIV(N,32), 256, 0, stream>>>(Q1, Q0, ecol, icnt, dinv, nullptr, N);
  // h~2 = dinv*relu(z2 @ W2 + b2)
  k_mgemm<64,2,1,false><<<CDIV(N,64), 256, 0, stream>>>(Q0, WT2, b2, Q1, N, nullptr, nullptr, dinv);
  // gather3: z3 = dinv*(sum + self)
  k_gather_q<128,false><<<CDIV(N,16), 256, 0, stream>>>(Q1, Q0, ecol, icnt, dinv, nullptr, N);
  // relu(z3 @ W3 + b3) + fused graph pooling
  k_mgemm<128,4,2,false><<<CDIV(N,64), 256, 0, stream>>>(Q0, WT3, b3, nullptr, N, batch, gsum, nullptr);
  // head
  k_gates<<<dim3(16, NG), 256, 0, stream>>>(gsum, cnt_g, wf, bf, wb, bb, gates);
  k_lstmfc<<<dim3(4, NG), 256, 0, stream>>>(gates, fw, fb, logits);
  k_smax<<<NG, 256, 0, stream>>>(logits, (float*)d_out);
}

// Round 14
// 203.222 us; speedup vs baseline: 1.6365x; 1.0422x over previous
//
#include <hip/hip_runtime.h>
#include <cstdint>
#include <cstddef>

#define CDIV(a,b) (((a)+(b)-1)/(b))
constexpr int NG = 64;
constexpr int CAP = 64;     // fixed in-edge capacity per node (Poisson(16): P(>64) ~ 1e-20)
constexpr int RBITS = 9;    // 512 nodes per dst-range
constexpr int NRMAX = 256;  // 196 ranges used at N=100k
constexpr int RCAP = 9216;  // per-range edge capacity (mean 8163, +11 sigma)

typedef _Float16 h4 __attribute__((ext_vector_type(4)));
typedef _Float16 h8 __attribute__((ext_vector_type(8)));
typedef float f4 __attribute__((ext_vector_type(4)));
typedef float f2 __attribute__((ext_vector_type(2)));

// fp8 e4m3 helpers (OCP on gfx950)
__device__ __forceinline__ void acc8(int2 v, float* a) {
  f2 p;
  p = __builtin_amdgcn_cvt_pk_f32_fp8(v.x, false); a[0] += p.x; a[1] += p.y;
  p = __builtin_amdgcn_cvt_pk_f32_fp8(v.x, true);  a[2] += p.x; a[3] += p.y;
  p = __builtin_amdgcn_cvt_pk_f32_fp8(v.y, false); a[4] += p.x; a[5] += p.y;
  p = __builtin_amdgcn_cvt_pk_f32_fp8(v.y, true);  a[6] += p.x; a[7] += p.y;
}
__device__ __forceinline__ int pack4(float x0, float x1, float x2, float x3) {
  int r = __builtin_amdgcn_cvt_pk_fp8_f32(x0, x1, 0, false);
  r = __builtin_amdgcn_cvt_pk_fp8_f32(x2, x3, r, true);
  return r;
}

// zero the small int region + zero the fp8 pad rows (node index N) of Q0/Q1
__global__ void k_init(int* zp, long zn, unsigned char* Q0, unsigned char* Q1, int N) {
  long i = (long)blockIdx.x*blockDim.x + threadIdx.x;
  long stride = (long)gridDim.x*blockDim.x;
  for (; i < zn; i += stride) zp[i] = 0;
  if (blockIdx.x == 0) {
    int t = threadIdx.x;
    if (t < 64)       Q0[(size_t)N*64 + t] = 0;
    else if (t < 128) Q1[(size_t)N*64 + (t-64)] = 0;
    else              Q1[(size_t)N*128 + (t-128)] = 0;   // 128 bytes: F128 pad
  }
}

// all three weight transposes (fp32 -> fp16, [K x nout] -> [nout x K]) in one launch
__global__ void k_wcvt_all(const float* __restrict__ W1, const float* __restrict__ W2,
                           const float* __restrict__ W3, _Float16* __restrict__ WT1,
                           _Float16* __restrict__ WT2, _Float16* __restrict__ WT3) {
  int idx = blockIdx.x*256 + threadIdx.x;
  if (idx < 8192) {                       // W1: K=128, nout=64
    int c = idx >> 7, k = idx & 127;
    WT1[idx] = (_Float16)W1[(size_t)k*64 + c];
  } else if (idx < 16384) {               // W2: K=64, nout=128
    int j = idx - 8192;
    int c = j >> 6, k = j & 63;
    WT2[j] = (_Float16)W2[(size_t)k*128 + c];
  } else if (idx < 49152) {               // W3: K=128, nout=256
    int j = idx - 16384;
    int c = j >> 7, k = j & 127;
    WT3[j] = (_Float16)W3[(size_t)k*256 + c];
  }
}

// phase 1: partition edges by dst-range; packed 4B records (dlocal<<17 | src)
__global__ __launch_bounds__(256) void k_part(
    const int* __restrict__ src, const int* __restrict__ dst,
    int* __restrict__ rngcur, unsigned* __restrict__ part, int E) {
  __shared__ int hcnt[NRMAX], hbase[NRMAX], hfill[NRMAX];
  int tid = threadIdx.x;
  int base = blockIdx.x * 4096;
  hcnt[tid] = 0;
  __syncthreads();
  unsigned val[16]; int rr[16];
  #pragma unroll
  for (int u = 0; u < 16; u++) {
    int e = base + u*256 + tid;
    rr[u] = -1;
    if (e < E) {
      int s = src[e], d = dst[e];
      rr[u] = d >> RBITS;
      val[u] = ((unsigned)(d & ((1<<RBITS)-1)) << 17) | (unsigned)s;
      atomicAdd(&hcnt[rr[u]], 1);
    }
  }
  __syncthreads();
  hfill[tid] = 0;
  if (hcnt[tid]) hbase[tid] = atomicAdd(&rngcur[tid], hcnt[tid]);
  __syncthreads();
  #pragma unroll
  for (int u = 0; u < 16; u++) {
    if (rr[u] >= 0) {
      int p = hbase[rr[u]] + atomicAdd(&hfill[rr[u]], 1);
      if (p < RCAP) part[(size_t)rr[u]*RCAP + p] = val[u];
    }
  }
}

// phase 2: LDS counting-sort per range -> coalesced CSR row writes (pad to x16 with
// sentinel N). Also emits per-node icnt/dinv and the per-graph node histogram.
__global__ __launch_bounds__(512) void k_csr3(
    const unsigned* __restrict__ part, const int* __restrict__ rngcur,
    const int* __restrict__ batch, int* __restrict__ icnt, float* __restrict__ dinv,
    int* __restrict__ ecol, int* __restrict__ cnt_g, int N) {
  __shared__ unsigned sorted[RCAP];            // 36 KB
  __shared__ int lcnt[512], lpos[512], lcur[512];
  __shared__ int wsum[8], hist[NG];
  int r = blockIdx.x;
  int tid = threadIdx.x;
  int cnt = min(rngcur[r], RCAP);
  int n0 = r << RBITS;
  int nn = min(512, N - n0);
  const unsigned* p = part + (size_t)r * RCAP;
  lcnt[tid] = 0; lcur[tid] = 0;
  if (tid < NG) hist[tid] = 0;
  __syncthreads();
  // pass 1: count per dst-local
  for (int i = tid; i < cnt; i += 512)
    atomicAdd(&lcnt[p[i] >> 17], 1);
  __syncthreads();
  // inclusive scan via wave shuffles + cross-wave offsets
  {
    int lane = tid & 63, wv = tid >> 6;
    int s = lcnt[tid];
    #pragma unroll
    for (int off = 1; off < 64; off <<= 1) {
      int t = __shfl_up(s, off, 64);
      if (lane >= off) s += t;
    }
    if (lane == 63) wsum[wv] = s;
    __syncthreads();
    int add = 0;
    #pragma unroll
    for (int j = 0; j < 8; j++) if (j < wv) add += wsum[j];
    lpos[tid] = s + add;
  }
  __syncthreads();
  // pass 2: place src into sorted LDS at exact CSR-local position
  for (int i = tid; i < cnt; i += 512) {
    unsigned v = p[i];
    int d = v >> 17;
    int q = (lpos[d] - lcnt[d]) + atomicAdd(&lcur[d], 1);
    sorted[q] = v & 131071u;
  }
  // node stats (need only lcnt)
  if (tid < nn) {
    int c = min(lcnt[tid], CAP);
    icnt[n0 + tid] = c;
    dinv[n0 + tid] = rsqrtf((float)(c + 1));
    atomicAdd(&hist[batch[n0 + tid]], 1);
  }
  __syncthreads();
  if (tid < NG && hist[tid]) atomicAdd(&cnt_g[tid], hist[tid]);
  // write-out: one wave per node; pad row to multiple of 16 with sentinel N
  int wv = tid >> 6, lane = tid & 63;
  for (int i = wv; i < nn; i += 8) {
    int c = min(lcnt[i], CAP);
    int pc = (c + 15) & ~15;
    if (lane < pc) {
      int v = (lane < c) ? (int)sorted[lpos[i] - lcnt[i] + lane] : N;
      ecol[(size_t)(n0 + i)*CAP + lane] = v;
    }
  }
}

// fp8 gather on premultiplied features: out[i] = dinv[i]*(sum_e y[s_e] + y[i])
// 8 B/lane = 8 fp8 elems; F=128: 16 lanes/node (4 nodes/wave); F=64: 8 lanes/node (8/wave).
template<int F, bool L1>
__global__ __launch_bounds__(256) void k_gather_q(
    const unsigned char* __restrict__ y, unsigned char* __restrict__ z,
    const int* __restrict__ ecol, const int* __restrict__ icnt,
    const float* __restrict__ dinv, const float* __restrict__ bias, int n) {
  constexpr int LPN = F / 8;
  constexpr int NPW = 64 / LPN;
  int wid = (int)((blockIdx.x*(size_t)blockDim.x + threadIdx.x) >> 6);
  int lane = threadIdx.x & 63;
  int sub = lane / LPN;
  int li  = lane % LPN;
  int gw = wid * NPW + sub;
  if (gw >= n) return;
  float di = dinv[gw];
  float a[8] = {};
  { int2 v = *(const int2*)(y + (size_t)gw*F + li*8); acc8(v, a); }
  int padc = (icnt[gw] + 15) & ~15;
  const int* col = ecol + (size_t)gw * CAP;
  for (int k = 0; k < padc; k += 16) {
    int4 c0 = *(const int4*)&col[k];
    int4 c1 = *(const int4*)&col[k+4];
    int4 c2 = *(const int4*)&col[k+8];
    int4 c3 = *(const int4*)&col[k+12];
    int c[16] = {c0.x,c0.y,c0.z,c0.w, c1.x,c1.y,c1.z,c1.w,
                 c2.x,c2.y,c2.z,c2.w, c3.x,c3.y,c3.z,c3.w};
    int2 v[16];
    #pragma unroll
    for (int u = 0; u < 16; u++)
      v[u] = *(const int2*)(y + (size_t)c[u]*F + li*8);
    #pragma unroll
    for (int u = 0; u < 16; u++) acc8(v[u], a);
  }
  if constexpr (L1) {
    #pragma unroll
    for (int j = 0; j < 8; j++)
      a[j] = di * fmaxf(di*a[j] + bias[li*8 + j], 0.f);
  } else {
    #pragma unroll
    for (int j = 0; j < 8; j++) a[j] *= di;
  }
  int2 o;
  o.x = pack4(a[0], a[1], a[2], a[3]);
  o.y = pack4(a[4], a[5], a[6], a[7]);
  *(int2*)(z + (size_t)gw*F + li*8) = o;
}

// MFMA GEMM: C[n x NOUT] = A[n x K] @ W, NOUT = CF*64, block = 64 rows x NOUT.
// EPI: 0=store (x rowscale), 1=bias+relu (x rowscale) store, 2=bias+relu + fused graph pool
// AF32: A fp32 (layer 1); else A fp8. C stored fp8 (EPI<=1). rs: optional per-row scale.
template<int K, int CF, int EPI, bool AF32>
__global__ __launch_bounds__(256, 2) void k_mgemm(
    const void* __restrict__ Av, const _Float16* __restrict__ WT,
    const float* __restrict__ bias, unsigned char* __restrict__ C,
    int n, const int* __restrict__ batch, float* __restrict__ gsum,
    const float* __restrict__ rs) {
  constexpr int KS = K / 32;
  constexpr int NOUT = CF * 64;
  constexpr int LDA = K + 8;
  __shared__ __align__(16) _Float16 sA[64][LDA];
  __shared__ float red[4][256];
  __shared__ int sBatch[64];
  int tid = threadIdx.x;
  int row0 = blockIdx.x * 64;
  int lane = tid & 63, wv = tid >> 6;
  int grp = lane >> 4, l16 = lane & 15;
  int wcol0 = wv * (CF * 16);

  {
    int srow = tid >> 2;
    bool ok = (row0 + srow) < n;
    if constexpr (AF32) {
      const float* A = (const float*)Av;
      #pragma unroll
      for (int u = 0; u < K/16; u++) {
        int c4 = (tid & 3) + 4*u;
        float4 v = ok ? *(const float4*)(A + (size_t)(row0+srow)*K + c4*4)
                      : make_float4(0.f,0.f,0.f,0.f);
        h4 o; o.x=(_Float16)v.x; o.y=(_Float16)v.y; o.z=(_Float16)v.z; o.w=(_Float16)v.w;
        *(h4*)&sA[srow][c4*4] = o;
      }
    } else {
      const unsigned char* A = (const unsigned char*)Av;
      #pragma unroll
      for (int u = 0; u < K/32; u++) {
        int off = ((tid & 3) + 4*u) * 8;
        int2 v = ok ? *(const int2*)(A + (size_t)(row0+srow)*K + off) : make_int2(0,0);
        f2 p0 = __builtin_amdgcn_cvt_pk_f32_fp8(v.x, false);
        f2 p1 = __builtin_amdgcn_cvt_pk_f32_fp8(v.x, true);
        f2 p2 = __builtin_amdgcn_cvt_pk_f32_fp8(v.y, false);
        f2 p3 = __builtin_amdgcn_cvt_pk_f32_fp8(v.y, true);
        h8 o;
        o[0]=(_Float16)p0.x; o[1]=(_Float16)p0.y; o[2]=(_Float16)p1.x; o[3]=(_Float16)p1.y;
        o[4]=(_Float16)p2.x; o[5]=(_Float16)p2.y; o[6]=(_Float16)p3.x; o[7]=(_Float16)p3.y;
        *(h8*)&sA[srow][off] = o;
      }
    }
  }
  if constexpr (EPI == 2) {
    if (tid < 64) sBatch[tid] = (row0 + tid < n) ? batch[row0 + tid] : -1;
  }

  h8 bfrag[KS][CF];
  #pragma unroll
  for (int ks = 0; ks < KS; ks++)
    #pragma unroll
    for (int cf = 0; cf < CF; cf++) {
      int col = wcol0 + cf*16 + l16;
      bfrag[ks][cf] = *(const h8*)(WT + (size_t)col*K + ks*32 + grp*8);
    }

  f4 acc[4][CF] = {};
  __syncthreads();

  #pragma unroll
  for (int ks = 0; ks < KS; ks++) {
    h8 af[4];
    #pragma unroll
    for (int rf = 0; rf < 4; rf++)
      af[rf] = *(const h8*)&sA[rf*16 + l16][ks*32 + grp*8];
    #pragma unroll
    for (int rf = 0; rf < 4; rf++)
      #pragma unroll
      for (int cf = 0; cf < CF; cf++)
        acc[rf][cf] = __builtin_amdgcn_mfma_f32_16x16x32_f16(
            af[rf], bfrag[ks][cf], acc[rf][cf], 0, 0, 0);
  }

  if constexpr (EPI <= 1) {
    #pragma unroll
    for (int rf = 0; rf < 4; rf++) {
      #pragma unroll
      for (int r = 0; r < 4; r++) {
        int row = row0 + rf*16 + grp*4 + r;
        if (row < n) {
          float rsv = rs ? rs[row] : 1.f;
          #pragma unroll
          for (int cf = 0; cf < CF; cf++) {
            int col = wcol0 + cf*16 + l16;
            float v = acc[rf][cf][r];
            if constexpr (EPI == 1) v = fmaxf(v + bias[col], 0.f);
            v *= rsv;
            int b = __builtin_amdgcn_cvt_pk_fp8_f32(v, v, 0, false);
            C[(size_t)row*NOUT + col] = (unsigned char)(b & 0xff);
          }
        }
      }
    }
  } else {
    float bv[CF];
    #pragma unroll
    for (int cf = 0; cf < CF; cf++) bv[cf] = bias[wcol0 + cf*16 + l16];
    #pragma unroll
    for (int rf = 0; rf < 4; rf++)
      #pragma unroll
      for (int cf = 0; cf < CF; cf++)
        #pragma unroll
        for (int r = 0; r < 4; r++)
          acc[rf][cf][r] = fmaxf(acc[rf][cf][r] + bv[cf], 0.f);
    __syncthreads();
    int g0 = sBatch[0];
    int g1 = batch[min(row0 + 63, n - 1)];
    for (int g = g0; g <= g1; ++g) {
      float p[CF] = {};
      #pragma unroll
      for (int rf = 0; rf < 4; rf++)
        #pragma unroll
        for (int r = 0; r < 4; r++) {
          int lrow = rf*16 + grp*4 + r;
          bool m = (sBatch[lrow] == g);
          #pragma unroll
          for (int cf = 0; cf < CF; cf++)
            if (m) p[cf] += acc[rf][cf][r];
        }
      #pragma unroll
      for (int cf = 0; cf < CF; cf++)
        red[grp][wcol0 + cf*16 + l16] = p[cf];
      __syncthreads();
      if (tid < NOUT) {
        float s = red[0][tid] + red[1][tid] + red[2][tid] + red[3][tid];
        atomicAdd(&gsum[g*256 + tid], s);
      }
      __syncthreads();
    }
  }
}

__device__ __forceinline__ float sigm(float x) { return 1.f / (1.f + expf(-x)); }

// gates[g][j] for j in [0,1024): [0,512)=forward, [512,1024)=backward.
__global__ __launch_bounds__(256) void k_gates(
    const float* __restrict__ gsum, const int* __restrict__ cnt_g,
    const float* __restrict__ wf, const float* __restrict__ bf,
    const float* __restrict__ wb, const float* __restrict__ bb,
    float* __restrict__ gates) {
  int g = blockIdx.y;
  int j0 = blockIdx.x * 64;
  int tid = threadIdx.x;
  __shared__ float pooled[256];
  float invc = 1.0f / fmaxf((float)cnt_g[g], 1.0f);
  pooled[tid] = gsum[g*256 + tid] * invc;
  __syncthreads();
  int jl = tid >> 2, ks = tid & 3;
  int j = j0 + jl;
  const float* wrow;
  float bias;
  if (j < 512) { wrow = wf + (size_t)j*256;        bias = bf[j]; }
  else         { wrow = wb + (size_t)(j-512)*256;  bias = bb[j-512]; }
  const float4* w4 = (const float4*)(wrow + ks*64);
  const float4* p4 = (const float4*)(&pooled[ks*64]);
  float acc = 0.f;
  #pragma unroll
  for (int i = 0; i < 16; i++) {
    float4 a = w4[i], b = p4[i];
    acc += a.x*b.x + a.y*b.y + a.z*b.z + a.w*b.w;
  }
  acc += __shfl_xor(acc, 1, 64);
  acc += __shfl_xor(acc, 2, 64);
  if (ks == 0) gates[(size_t)g*1024 + j] = acc + bias;
}

// LSTM nonlinearity (T=1, zero state) + FC strip of 125 columns.
__global__ __launch_bounds__(256) void k_lstmfc(
    const float* __restrict__ gates, const float* __restrict__ fw,
    const float* __restrict__ fb, float* __restrict__ logits) {
  int g = blockIdx.y;
  int c0 = blockIdx.x * 125;
  int tid = threadIdx.x;
  __shared__ float gg[1024];
  __shared__ float lstm[256];
  __shared__ float sred[256];
  #pragma unroll
  for (int u = 0; u < 4; u++) gg[tid + u*256] = gates[(size_t)g*1024 + tid + u*256];
  __syncthreads();
  if (tid < 128) {
    float i = gg[tid], z = gg[256+tid], o = gg[384+tid];
    float cc = sigm(i)*tanhf(z);
    lstm[tid] = sigm(o)*tanhf(cc);
  } else {
    int u = tid - 128;
    float i = gg[512+u], z = gg[768+u], o = gg[896+u];
    float cc = sigm(i)*tanhf(z);
    lstm[128+u] = sigm(o)*tanhf(cc);
  }
  __syncthreads();
  int kh = tid >> 7;
  int cl = tid & 127;
  float acc = 0.f;
  if (cl < 125) {
    const float* fcol = fw + (size_t)kh*128*500 + (c0 + cl);
    #pragma unroll 8
    for (int k = 0; k < 128; k++)
      acc += lstm[kh*128 + k] * fcol[(size_t)k*500];
  }
  sred[tid] = acc;
  __syncthreads();
  if (tid < 125)
    logits[(size_t)g*500 + c0 + tid] = sred[tid] + sred[tid+128] + fb[c0 + tid];
}

// log_softmax over 500 logits per graph
__global__ __launch_bounds__(256) void k_smax(
    const float* __restrict__ logits, float* __restrict__ out) {
  int g = blockIdx.x, tid = threadIdx.x;
  __shared__ float sred[256];
  float l0 = logits[(size_t)g*500 + tid];
  float l1 = (tid < 244) ? logits[(size_t)g*500 + 256 + tid] : -1e30f;
  float m = fmaxf(l0, l1);
  sred[tid] = m; __syncthreads();
  for (int d = 128; d > 0; d >>= 1) {
    if (tid < d) sred[tid] = fmaxf(sred[tid], sred[tid+d]);
    __syncthreads();
  }
  float mx = sred[0]; __syncthreads();
  float s = expf(l0 - mx) + ((tid < 244) ? expf(l1 - mx) : 0.f);
  sred[tid] = s; __syncthreads();
  for (int d = 128; d > 0; d >>= 1) {
    if (tid < d) sred[tid] += sred[tid+d];
    __syncthreads();
  }
  float lse = logf(sred[0]) + mx;
  out[(size_t)g*500 + tid] = l0 - lse;
  if (tid < 244) out[(size_t)g*500 + 256 + tid] = l1 - lse;
}

extern "C" void kernel_launch(void* const* d_in, const int* in_sizes, int n_in,
                              void* d_out, int out_size, void* d_ws, size_t ws_size,
                              hipStream_t stream) {
  const float* x     = (const float*)d_in[0];
  const int*   ei    = (const int*)d_in[1];
  const int*   batch = (const int*)d_in[2];
  const float* W1 = (const float*)d_in[3];  const float* b1 = (const float*)d_in[4];
  const float* W2 = (const float*)d_in[5];  const float* b2 = (const float*)d_in[6];
  const float* W3 = (const float*)d_in[7];  const float* b3 = (const float*)d_in[8];
  const float* wf = (const float*)d_in[9];  const float* bf = (const float*)d_in[11];
  const float* wb = (const float*)d_in[12]; const float* bb = (const float*)d_in[14];
  const float* fw = (const float*)d_in[15]; const float* fb = (const float*)d_in[16];
  int N = in_sizes[2];
  int E = in_sizes[1] / 2;
  const int* src = ei;
  const int* dst = ei + E;
  int NR = CDIV(N, 1 << RBITS);            // 196 ranges

  char* w = (char*)d_ws;
  auto alloc = [&](size_t bytes) { char* p = w; w += (bytes + 255) / 256 * 256; return p; };
  int*   cnt_g  = (int*)  alloc(NG*4);
  int*   rngcur = (int*)  alloc(NRMAX*4);
  float* gsum   = (float*)alloc(NG*256*4);
  char*  zero_end = w;
  int*   icnt  = (int*)  alloc((size_t)N*4);
  float* dinv  = (float*)alloc((size_t)N*4);
  unsigned* part = (unsigned*)alloc((size_t)NR*RCAP*4);
  int*   ecol  = (int*)  alloc((size_t)N*CAP*4);
  unsigned char* Q0 = (unsigned char*)alloc(((size_t)N+1)*128);
  unsigned char* Q1 = (unsigned char*)alloc(((size_t)N+1)*128);
  _Float16* WT1 = (_Float16*)alloc(128*64*2);
  _Float16* WT2 = (_Float16*)alloc(64*128*2);
  _Float16* WT3 = (_Float16*)alloc(128*256*2);
  float* gates  = (float*)alloc((size_t)NG*1024*4);
  float* logits = (float*)alloc((size_t)NG*500*4);

  long zwords = (zero_end - (char*)cnt_g) / 4;
  k_init<<<64, 256, 0, stream>>>(cnt_g, zwords, Q0, Q1, N);
  k_wcvt_all<<<192, 256, 0, stream>>>(W1, W2, W3, WT1, WT2, WT3);
  k_part<<<CDIV(E,4096), 256, 0, stream>>>(src, dst, rngcur, part, E);
  k_csr3<<<NR, 512, 0, stream>>>(part, rngcur, batch, icnt, dinv, ecol, cnt_g, N);

  // layer 1: y~1 = dinv*(x @ W1)  (MFMA fp32->fp16, fp8 store, rowscale fused)
  k_mgemm<128,1,0,true><<<CDIV(N,64), 256, 0, stream>>>(x, WT1, nullptr, Q0, N, nullptr, nullptr, dinv);
  // gather1: h~1 = dinv*relu(dinv*(sum + self) + b1)
  k_gather_q<64,true><<<CDIV(N,32), 256, 0, stream>>>(Q0, Q1, ecol, icnt, dinv, b1, N);
  // gather2: z2 = dinv*(sum + self)
  k_gather_q<64,false><<<CDIV(N,32), 256, 0, stream>>>(Q1, Q0, ecol, icnt, dinv, nullptr, N);
  // h~2 = dinv*relu(z2 @ W2 + b2)
  k_mgemm<64,2,1,false><<<CDIV(N,64), 256, 0, stream>>>(Q0, WT2, b2, Q1, N, nullptr, nullptr, dinv);
  // gather3: z3 = dinv*(sum + self)
  k_gather_q<128,false><<<CDIV(N,16), 256, 0, stream>>>(Q1, Q0, ecol, icnt, dinv, nullptr, N);
  // relu(z3 @ W3 + b3) + fused graph pooling
  k_mgemm<128,4,2,false><<<CDIV(N,64), 256, 0, stream>>>(Q0, WT3, b3, nullptr, N, batch, gsum, nullptr);
  // head
  k_gates<<<dim3(16, NG), 256, 0, stream>>>(gsum, cnt_g, wf, bf, wb, bb, gates);
  k_lstmfc<<<dim3(4, NG), 256, 0, stream>>>(gates, fw, fb, logits);
  k_smax<<<NG, 256, 0, stream>>>(logits, (float*)d_out);
}

// Round 15
// 197.552 us; speedup vs baseline: 1.6835x; 1.0287x over previous
//
#include <hip/hip_runtime.h>
#include <cstdint>
#include <cstddef>

#define CDIV(a,b) (((a)+(b)-1)/(b))
constexpr int NG = 64;
constexpr int CAP = 64;     // fixed in-edge capacity per node (Poisson(16): P(>64) ~ 1e-20)
constexpr int RBITS = 9;    // 512 nodes per dst-range
constexpr int NRMAX = 256;  // 196 ranges used at N=100k
constexpr int RCAP = 9216;  // per-range edge capacity (mean 8163, +11 sigma)

typedef _Float16 h4 __attribute__((ext_vector_type(4)));
typedef _Float16 h8 __attribute__((ext_vector_type(8)));
typedef float f4 __attribute__((ext_vector_type(4)));
typedef float f2 __attribute__((ext_vector_type(2)));

// fp8 e4m3 helpers (OCP on gfx950)
__device__ __forceinline__ void acc8(int2 v, float* a) {
  f2 p;
  p = __builtin_amdgcn_cvt_pk_f32_fp8(v.x, false); a[0] += p.x; a[1] += p.y;
  p = __builtin_amdgcn_cvt_pk_f32_fp8(v.x, true);  a[2] += p.x; a[3] += p.y;
  p = __builtin_amdgcn_cvt_pk_f32_fp8(v.y, false); a[4] += p.x; a[5] += p.y;
  p = __builtin_amdgcn_cvt_pk_f32_fp8(v.y, true);  a[6] += p.x; a[7] += p.y;
}
__device__ __forceinline__ int pack4(float x0, float x1, float x2, float x3) {
  int r = __builtin_amdgcn_cvt_pk_fp8_f32(x0, x1, 0, false);
  r = __builtin_amdgcn_cvt_pk_fp8_f32(x2, x3, r, true);
  return r;
}

// comboA: block 0 = pad-row zeroing; blocks [1,193) = weight transposes;
// blocks [193, 193+NBPART) = edge partition. (rngcur/cnt_g/gsum zeroed by memsetAsync.)
__global__ __launch_bounds__(256) void k_comboA(
    unsigned char* Q0, unsigned char* Q1, int N,
    const float* __restrict__ W1, const float* __restrict__ W2,
    const float* __restrict__ W3, _Float16* __restrict__ WT1,
    _Float16* __restrict__ WT2, _Float16* __restrict__ WT3,
    const int* __restrict__ src, const int* __restrict__ dst,
    int* __restrict__ rngcur, unsigned* __restrict__ part, int E) {
  int b = blockIdx.x;
  int tid = threadIdx.x;
  if (b == 0) {
    if (tid < 64)       Q0[(size_t)N*64 + tid] = 0;
    else if (tid < 128) Q1[(size_t)N*64 + (tid-64)] = 0;
    else                Q0[(size_t)N*128 + (tid-128)] = 0;
    return;
  }
  if (b < 193) {
    int idx = (b-1)*256 + tid;
    if (idx < 8192) {                       // W1: K=128, nout=64
      int c = idx >> 7, k = idx & 127;
      WT1[idx] = (_Float16)W1[(size_t)k*64 + c];
    } else if (idx < 16384) {               // W2: K=64, nout=128
      int j = idx - 8192;
      int c = j >> 6, k = j & 63;
      WT2[j] = (_Float16)W2[(size_t)k*128 + c];
    } else if (idx < 49152) {               // W3: K=128, nout=256
      int j = idx - 16384;
      int c = j >> 7, k = j & 127;
      WT3[j] = (_Float16)W3[(size_t)k*256 + c];
    }
    return;
  }
  // edge partition: packed 4B records (dlocal<<17 | src) into per-range regions
  __shared__ int hcnt[NRMAX], hbase[NRMAX], hfill[NRMAX];
  int base = (b - 193) * 4096;
  hcnt[tid] = 0;
  __syncthreads();
  unsigned val[16]; int rr[16];
  #pragma unroll
  for (int u = 0; u < 16; u++) {
    int e = base + u*256 + tid;
    rr[u] = -1;
    if (e < E) {
      int s = src[e], d = dst[e];
      rr[u] = d >> RBITS;
      val[u] = ((unsigned)(d & ((1<<RBITS)-1)) << 17) | (unsigned)s;
      atomicAdd(&hcnt[rr[u]], 1);
    }
  }
  __syncthreads();
  hfill[tid] = 0;
  if (hcnt[tid]) hbase[tid] = atomicAdd(&rngcur[tid], hcnt[tid]);
  __syncthreads();
  #pragma unroll
  for (int u = 0; u < 16; u++) {
    if (rr[u] >= 0) {
      int p = hbase[rr[u]] + atomicAdd(&hfill[rr[u]], 1);
      if (p < RCAP) part[(size_t)rr[u]*RCAP + p] = val[u];
    }
  }
}

// LDS counting-sort per range -> coalesced CSR rows (pad to x16 with sentinel N).
// Also emits per-node icnt/dinv and the per-graph node histogram.
__global__ __launch_bounds__(512) void k_csr3(
    const unsigned* __restrict__ part, const int* __restrict__ rngcur,
    const int* __restrict__ batch, int* __restrict__ icnt, float* __restrict__ dinv,
    int* __restrict__ ecol, int* __restrict__ cnt_g, int N) {
  __shared__ unsigned sorted[RCAP];            // 36 KB
  __shared__ int lcnt[512], lpos[512], lcur[512];
  __shared__ int wsum[8], hist[NG];
  int r = blockIdx.x;
  int tid = threadIdx.x;
  int cnt = min(rngcur[r], RCAP);
  int n0 = r << RBITS;
  int nn = min(512, N - n0);
  const unsigned* p = part + (size_t)r * RCAP;
  lcnt[tid] = 0; lcur[tid] = 0;
  if (tid < NG) hist[tid] = 0;
  __syncthreads();
  for (int i = tid; i < cnt; i += 512)
    atomicAdd(&lcnt[p[i] >> 17], 1);
  __syncthreads();
  {
    int lane = tid & 63, wv = tid >> 6;
    int s = lcnt[tid];
    #pragma unroll
    for (int off = 1; off < 64; off <<= 1) {
      int t = __shfl_up(s, off, 64);
      if (lane >= off) s += t;
    }
    if (lane == 63) wsum[wv] = s;
    __syncthreads();
    int add = 0;
    #pragma unroll
    for (int j = 0; j < 8; j++) if (j < wv) add += wsum[j];
    lpos[tid] = s + add;
  }
  __syncthreads();
  for (int i = tid; i < cnt; i += 512) {
    unsigned v = p[i];
    int d = v >> 17;
    int q = (lpos[d] - lcnt[d]) + atomicAdd(&lcur[d], 1);
    sorted[q] = v & 131071u;
  }
  if (tid < nn) {
    int c = min(lcnt[tid], CAP);
    icnt[n0 + tid] = c;
    dinv[n0 + tid] = rsqrtf((float)(c + 1));
    atomicAdd(&hist[batch[n0 + tid]], 1);
  }
  __syncthreads();
  if (tid < NG && hist[tid]) atomicAdd(&cnt_g[tid], hist[tid]);
  int wv = tid >> 6, lane = tid & 63;
  for (int i = wv; i < nn; i += 8) {
    int c = min(lcnt[i], CAP);
    int pc = (c + 15) & ~15;
    if (lane < pc) {
      int v = (lane < c) ? (int)sorted[lpos[i] - lcnt[i] + lane] : N;
      ecol[(size_t)(n0 + i)*CAP + lane] = v;
    }
  }
}

// fp8 gather on premultiplied features: out[i] = dinv[i]*relu(dinv[i]*(sum+self)+bias)*dinv? (L1)
// 8 B/lane = 8 fp8 elems; F=64: 8 lanes/node (8 nodes/wave).
template<int F, bool L1>
__global__ __launch_bounds__(256) void k_gather_q(
    const unsigned char* __restrict__ y, unsigned char* __restrict__ z,
    const int* __restrict__ ecol, const int* __restrict__ icnt,
    const float* __restrict__ dinv, const float* __restrict__ bias, int n) {
  constexpr int LPN = F / 8;
  constexpr int NPW = 64 / LPN;
  int wid = (int)((blockIdx.x*(size_t)blockDim.x + threadIdx.x) >> 6);
  int lane = threadIdx.x & 63;
  int sub = lane / LPN;
  int li  = lane % LPN;
  int gw = wid * NPW + sub;
  if (gw >= n) return;
  float di = dinv[gw];
  float a[8] = {};
  { int2 v = *(const int2*)(y + (size_t)gw*F + li*8); acc8(v, a); }
  int padc = (icnt[gw] + 15) & ~15;
  const int* col = ecol + (size_t)gw * CAP;
  for (int k = 0; k < padc; k += 16) {
    int4 c0 = *(const int4*)&col[k];
    int4 c1 = *(const int4*)&col[k+4];
    int4 c2 = *(const int4*)&col[k+8];
    int4 c3 = *(const int4*)&col[k+12];
    int c[16] = {c0.x,c0.y,c0.z,c0.w, c1.x,c1.y,c1.z,c1.w,
                 c2.x,c2.y,c2.z,c2.w, c3.x,c3.y,c3.z,c3.w};
    int2 v[16];
    #pragma unroll
    for (int u = 0; u < 16; u++)
      v[u] = *(const int2*)(y + (size_t)c[u]*F + li*8);
    #pragma unroll
    for (int u = 0; u < 16; u++) acc8(v[u], a);
  }
  if constexpr (L1) {
    #pragma unroll
    for (int j = 0; j < 8; j++)
      a[j] = di * fmaxf(di*a[j] + bias[li*8 + j], 0.f);
  } else {
    #pragma unroll
    for (int j = 0; j < 8; j++) a[j] *= di;
  }
  int2 o;
  o.x = pack4(a[0], a[1], a[2], a[3]);
  o.y = pack4(a[4], a[5], a[6], a[7]);
  *(int2*)(z + (size_t)gw*F + li*8) = o;
}

// MFMA GEMM: C[n x NOUT] = A[n x K] @ W, NOUT = CF*64, block = 64 rows x NOUT.
// EPI: 0=store (x rowscale), 1=bias+relu (x rowscale) store, 2=bias+relu + fused graph pool
// GM: 0 = A fp32 rows; 2 = A rows GATHERED from fp8 table (z = dinv*(sum+self)), fp16 LDS.
template<int K, int CF, int EPI, int GM>
__global__ __launch_bounds__(256, 2) void k_mgemm(
    const void* __restrict__ Av, const _Float16* __restrict__ WT,
    const float* __restrict__ bias, unsigned char* __restrict__ C,
    int n, const int* __restrict__ batch, float* __restrict__ gsum,
    const float* __restrict__ rs, const int* __restrict__ ecol,
    const int* __restrict__ icnt, const float* __restrict__ dinvp) {
  constexpr int KS = K / 32;
  constexpr int NOUT = CF * 64;
  constexpr int LDA = K + 8;
  __shared__ __align__(16) _Float16 sA[64][LDA];
  __shared__ float red[4][256];
  __shared__ int sBatch[64];
  int tid = threadIdx.x;
  int row0 = blockIdx.x * 64;
  int lane = tid & 63, wv = tid >> 6;
  int grp = lane >> 4, l16 = lane & 15;
  int wcol0 = wv * (CF * 16);

  if constexpr (GM == 0) {
    const float* A = (const float*)Av;
    int srow = tid >> 2;
    bool ok = (row0 + srow) < n;
    #pragma unroll
    for (int u = 0; u < K/16; u++) {
      int c4 = (tid & 3) + 4*u;
      float4 v = ok ? *(const float4*)(A + (size_t)(row0+srow)*K + c4*4)
                    : make_float4(0.f,0.f,0.f,0.f);
      h4 o; o.x=(_Float16)v.x; o.y=(_Float16)v.y; o.z=(_Float16)v.z; o.w=(_Float16)v.w;
      *(h4*)&sA[srow][c4*4] = o;
    }
  } else {
    // gather-fused staging: row = dinv*(sum_neighbors + self) from fp8 table
    constexpr int SL = K / 8;                 // 8-byte slices per row
    const unsigned char* Y = (const unsigned char*)Av;
    for (int un = tid; un < 64*SL; un += 256) {
      int row = un / SL, sl = un % SL;
      int grow = row0 + row;
      float a[8] = {};
      if (grow < n) {
        { int2 v0 = *(const int2*)(Y + (size_t)grow*K + sl*8); acc8(v0, a); }
        int padc = (icnt[grow] + 15) & ~15;
        const int* col = ecol + (size_t)grow * CAP;
        for (int k = 0; k < padc; k += 16) {
          int4 c0 = *(const int4*)&col[k];
          int4 c1 = *(const int4*)&col[k+4];
          int4 c2 = *(const int4*)&col[k+8];
          int4 c3 = *(const int4*)&col[k+12];
          int c[16] = {c0.x,c0.y,c0.z,c0.w, c1.x,c1.y,c1.z,c1.w,
                       c2.x,c2.y,c2.z,c2.w, c3.x,c3.y,c3.z,c3.w};
          int2 v[16];
          #pragma unroll
          for (int u = 0; u < 16; u++)
            v[u] = *(const int2*)(Y + (size_t)c[u]*K + sl*8);
          #pragma unroll
          for (int u = 0; u < 16; u++) acc8(v[u], a);
        }
        float di = dinvp[grow];
        #pragma unroll
        for (int j = 0; j < 8; j++) a[j] *= di;
      }
      h8 o;
      #pragma unroll
      for (int j = 0; j < 8; j++) o[j] = (_Float16)a[j];
      *(h8*)&sA[row][sl*8] = o;
    }
  }
  if constexpr (EPI == 2) {
    if (tid < 64) sBatch[tid] = (row0 + tid < n) ? batch[row0 + tid] : -1;
  }

  h8 bfrag[KS][CF];
  #pragma unroll
  for (int ks = 0; ks < KS; ks++)
    #pragma unroll
    for (int cf = 0; cf < CF; cf++) {
      int col = wcol0 + cf*16 + l16;
      bfrag[ks][cf] = *(const h8*)(WT + (size_t)col*K + ks*32 + grp*8);
    }

  f4 acc[4][CF] = {};
  __syncthreads();

  #pragma unroll
  for (int ks = 0; ks < KS; ks++) {
    h8 af[4];
    #pragma unroll
    for (int rf = 0; rf < 4; rf++)
      af[rf] = *(const h8*)&sA[rf*16 + l16][ks*32 + grp*8];
    #pragma unroll
    for (int rf = 0; rf < 4; rf++)
      #pragma unroll
      for (int cf = 0; cf < CF; cf++)
        acc[rf][cf] = __builtin_amdgcn_mfma_f32_16x16x32_f16(
            af[rf], bfrag[ks][cf], acc[rf][cf], 0, 0, 0);
  }

  if constexpr (EPI <= 1) {
    #pragma unroll
    for (int rf = 0; rf < 4; rf++) {
      #pragma unroll
      for (int r = 0; r < 4; r++) {
        int row = row0 + rf*16 + grp*4 + r;
        if (row < n) {
          float rsv = rs ? rs[row] : 1.f;
          #pragma unroll
          for (int cf = 0; cf < CF; cf++) {
            int col = wcol0 + cf*16 + l16;
            float v = acc[rf][cf][r];
            if constexpr (EPI == 1) v = fmaxf(v + bias[col], 0.f);
            v *= rsv;
            int b = __builtin_amdgcn_cvt_pk_fp8_f32(v, v, 0, false);
            C[(size_t)row*NOUT + col] = (unsigned char)(b & 0xff);
          }
        }
      }
    }
  } else {
    float bv[CF];
    #pragma unroll
    for (int cf = 0; cf < CF; cf++) bv[cf] = bias[wcol0 + cf*16 + l16];
    #pragma unroll
    for (int rf = 0; rf < 4; rf++)
      #pragma unroll
      for (int cf = 0; cf < CF; cf++)
        #pragma unroll
        for (int r = 0; r < 4; r++)
          acc[rf][cf][r] = fmaxf(acc[rf][cf][r] + bv[cf], 0.f);
    __syncthreads();
    int g0 = sBatch[0];
    int g1 = batch[min(row0 + 63, n - 1)];
    for (int g = g0; g <= g1; ++g) {
      float p[CF] = {};
      #pragma unroll
      for (int rf = 0; rf < 4; rf++)
        #pragma unroll
        for (int r = 0; r < 4; r++) {
          int lrow = rf*16 + grp*4 + r;
          bool m = (sBatch[lrow] == g);
          #pragma unroll
          for (int cf = 0; cf < CF; cf++)
            if (m) p[cf] += acc[rf][cf][r];
        }
      #pragma unroll
      for (int cf = 0; cf < CF; cf++)
        red[grp][wcol0 + cf*16 + l16] = p[cf];
      __syncthreads();
      if (tid < NOUT) {
        float s = red[0][tid] + red[1][tid] + red[2][tid] + red[3][tid];
        atomicAdd(&gsum[g*256 + tid], s);
      }
      __syncthreads();
    }
  }
}

__device__ __forceinline__ float sigm(float x) { return 1.f / (1.f + expf(-x)); }

// gates[g][j] for j in [0,1024): [0,512)=forward, [512,1024)=backward.
__global__ __launch_bounds__(256) void k_gates(
    const float* __restrict__ gsum, const int* __restrict__ cnt_g,
    const float* __restrict__ wf, const float* __restrict__ bf,
    const float* __restrict__ wb, const float* __restrict__ bb,
    float* __restrict__ gates) {
  int g = blockIdx.y;
  int j0 = blockIdx.x * 64;
  int tid = threadIdx.x;
  __shared__ float pooled[256];
  float invc = 1.0f / fmaxf((float)cnt_g[g], 1.0f);
  pooled[tid] = gsum[g*256 + tid] * invc;
  __syncthreads();
  int jl = tid >> 2, ks = tid & 3;
  int j = j0 + jl;
  const float* wrow;
  float bias;
  if (j < 512) { wrow = wf + (size_t)j*256;        bias = bf[j]; }
  else         { wrow = wb + (size_t)(j-512)*256;  bias = bb[j-512]; }
  const float4* w4 = (const float4*)(wrow + ks*64);
  const float4* p4 = (const float4*)(&pooled[ks*64]);
  float acc = 0.f;
  #pragma unroll
  for (int i = 0; i < 16; i++) {
    float4 a = w4[i], b = p4[i];
    acc += a.x*b.x + a.y*b.y + a.z*b.z + a.w*b.w;
  }
  acc += __shfl_xor(acc, 1, 64);
  acc += __shfl_xor(acc, 2, 64);
  if (ks == 0) gates[(size_t)g*1024 + j] = acc + bias;
}

// LSTM nonlinearity (T=1, zero state) + FC strip of 125 columns.
__global__ __launch_bounds__(256) void k_lstmfc(
    const float* __restrict__ gates, const float* __restrict__ fw,
    const float* __restrict__ fb, float* __restrict__ logits) {
  int g = blockIdx.y;
  int c0 = blockIdx.x * 125;
  int tid = threadIdx.x;
  __shared__ float gg[1024];
  __shared__ float lstm[256];
  __shared__ float sred[256];
  #pragma unroll
  for (int u = 0; u < 4; u++) gg[tid + u*256] = gates[(size_t)g*1024 + tid + u*256];
  __syncthreads();
  if (tid < 128) {
    float i = gg[tid], z = gg[256+tid], o = gg[384+tid];
    float cc = sigm(i)*tanhf(z);
    lstm[tid] = sigm(o)*tanhf(cc);
  } else {
    int u = tid - 128;
    float i = gg[512+u], z = gg[768+u], o = gg[896+u];
    float cc = sigm(i)*tanhf(z);
    lstm[128+u] = sigm(o)*tanhf(cc);
  }
  __syncthreads();
  int kh = tid >> 7;
  int cl = tid & 127;
  float acc = 0.f;
  if (cl < 125) {
    const float* fcol = fw + (size_t)kh*128*500 + (c0 + cl);
    #pragma unroll 8
    for (int k = 0; k < 128; k++)
      acc += lstm[kh*128 + k] * fcol[(size_t)k*500];
  }
  sred[tid] = acc;
  __syncthreads();
  if (tid < 125)
    logits[(size_t)g*500 + c0 + tid] = sred[tid] + sred[tid+128] + fb[c0 + tid];
}

// log_softmax over 500 logits per graph
__global__ __launch_bounds__(256) void k_smax(
    const float* __restrict__ logits, float* __restrict__ out) {
  int g = blockIdx.x, tid = threadIdx.x;
  __shared__ float sred[256];
  float l0 = logits[(size_t)g*500 + tid];
  float l1 = (tid < 244) ? logits[(size_t)g*500 + 256 + tid] : -1e30f;
  float m = fmaxf(l0, l1);
  sred[tid] = m; __syncthreads();
  for (int d = 128; d > 0; d >>= 1) {
    if (tid < d) sred[tid] = fmaxf(sred[tid], sred[tid+d]);
    __syncthreads();
  }
  float mx = sred[0]; __syncthreads();
  float s = expf(l0 - mx) + ((tid < 244) ? expf(l1 - mx) : 0.f);
  sred[tid] = s; __syncthreads();
  for (int d = 128; d > 0; d >>= 1) {
    if (tid < d) sred[tid] += sred[tid+d];
    __syncthreads();
  }
  float lse = logf(sred[0]) + mx;
  out[(size_t)g*500 + tid] = l0 - lse;
  if (tid < 244) out[(size_t)g*500 + 256 + tid] = l1 - lse;
}

extern "C" void kernel_launch(void* const* d_in, const int* in_sizes, int n_in,
                              void* d_out, int out_size, void* d_ws, size_t ws_size,
                              hipStream_t stream) {
  const float* x     = (const float*)d_in[0];
  const int*   ei    = (const int*)d_in[1];
  const int*   batch = (const int*)d_in[2];
  const float* W1 = (const float*)d_in[3];  const float* b1 = (const float*)d_in[4];
  const float* W2 = (const float*)d_in[5];  const float* b2 = (const float*)d_in[6];
  const float* W3 = (const float*)d_in[7];  const float* b3 = (const float*)d_in[8];
  const float* wf = (const float*)d_in[9];  const float* bf = (const float*)d_in[11];
  const float* wb = (const float*)d_in[12]; const float* bb = (const float*)d_in[14];
  const float* fw = (const float*)d_in[15]; const float* fb = (const float*)d_in[16];
  int N = in_sizes[2];
  int E = in_sizes[1] / 2;
  const int* src = ei;
  const int* dst = ei + E;
  int NR = CDIV(N, 1 << RBITS);            // 196 ranges
  int NBPART = CDIV(E, 4096);              // 391 partition blocks

  char* w = (char*)d_ws;
  auto alloc = [&](size_t bytes) { char* p = w; w += (bytes + 255) / 256 * 256; return p; };
  int*   cnt_g  = (int*)  alloc(NG*4);
  int*   rngcur = (int*)  alloc(NRMAX*4);
  float* gsum   = (float*)alloc(NG*256*4);
  char*  zero_end = w;
  int*   icnt  = (int*)  alloc((size_t)N*4);
  float* dinv  = (float*)alloc((size_t)N*4);
  unsigned* part = (unsigned*)alloc((size_t)NR*RCAP*4);
  int*   ecol  = (int*)  alloc((size_t)N*CAP*4);
  unsigned char* Q0 = (unsigned char*)alloc(((size_t)N+1)*128);
  unsigned char* Q1 = (unsigned char*)alloc(((size_t)N+1)*128);
  _Float16* WT1 = (_Float16*)alloc(128*64*2);
  _Float16* WT2 = (_Float16*)alloc(64*128*2);
  _Float16* WT3 = (_Float16*)alloc(128*256*2);
  float* gates  = (float*)alloc((size_t)NG*1024*4);
  float* logits = (float*)alloc((size_t)NG*500*4);

  size_t zbytes = (size_t)(zero_end - (char*)cnt_g);
  hipMemsetAsync(cnt_g, 0, zbytes, stream);
  k_comboA<<<193 + NBPART, 256, 0, stream>>>(Q0, Q1, N, W1, W2, W3, WT1, WT2, WT3,
                                             src, dst, rngcur, part, E);
  k_csr3<<<NR, 512, 0, stream>>>(part, rngcur, batch, icnt, dinv, ecol, cnt_g, N);

  // layer 1: y~1 = dinv*(x @ W1)  (MFMA fp32->fp16, fp8 store, rowscale fused)
  k_mgemm<128,1,0,0><<<CDIV(N,64), 256, 0, stream>>>(x, WT1, nullptr, Q0, N,
      nullptr, nullptr, dinv, nullptr, nullptr, nullptr);
  // gather1: h~1 = dinv*relu(dinv*(sum + self) + b1)
  k_gather_q<64,true><<<CDIV(N,32), 256, 0, stream>>>(Q0, Q1, ecol, icnt, dinv, b1, N);
  // fused gather2+gemm2: z2 gathered from Q1 in-staging; h~2 = dinv*relu(z2@W2+b2) -> Q0 (F=128)
  k_mgemm<64,2,1,2><<<CDIV(N,64), 256, 0, stream>>>(Q1, WT2, b2, Q0, N,
      nullptr, nullptr, dinv, ecol, icnt, dinv);
  // fused gather3+gemm3: z3 gathered from Q0 in-staging; relu(z3@W3+b3) + graph pooling
  k_mgemm<128,4,2,2><<<CDIV(N,64), 256, 0, stream>>>(Q0, WT3, b3, nullptr, N,
      batch, gsum, nullptr, ecol, icnt, dinv);
  // head
  k_gates<<<dim3(16, NG), 256, 0, stream>>>(gsum, cnt_g, wf, bf, wb, bb, gates);
  k_lstmfc<<<dim3(4, NG), 256, 0, stream>>>(gates, fw, fb, logits);
  k_smax<<<NG, 256, 0, stream>>>(logits, (float*)d_out);
}